// Round 4
// baseline (208.355 us; speedup 1.0000x reference)
//
#include <hip/hip_runtime.h>
#include <math.h>
#include <stdint.h>

#define BATCH 8192
#define NS 4

typedef _Float16 f16;
typedef _Float16 f16x2 __attribute__((ext_vector_type(2)));
typedef _Float16 f16x8 __attribute__((ext_vector_type(8)));
typedef float f32x4 __attribute__((ext_vector_type(4)));

__device__ __forceinline__ uint32_t pk2(float a, float b) {
    return __builtin_bit_cast(uint32_t, __builtin_amdgcn_cvt_pkrtz(a, b));
}
__device__ __forceinline__ uint32_t rfl_u(uint32_t v) {
    return (uint32_t)__builtin_amdgcn_readfirstlane((int)v);
}

// -----------------------------------------------------------------------------
// Pack kernel:
//  w1p16 [64][800] f16 : w1p16[o][k] = f1w[o*784 + (k&15)*49 + (k>>4)], k>=784 -> 0
//  w2a   [16][96]  f16 : w2a[oc][k]  = c2w[oc*72 + (k&7)*9 + (k>>3)],  k>=72  -> 0
//        (k = tap*8 + ic : 8 input channels contiguous per tap)
//  w1pk  u32[40]       : [t*4+pr] = pack(c1w[2pr][t], c1w[2pr+1][t]); [36+pr] = bias pairs
// -----------------------------------------------------------------------------
__global__ __launch_bounds__(256) void pack_weights(
    const float* __restrict__ f1w, const float* __restrict__ c2w,
    const float* __restrict__ c1w, const float* __restrict__ c1b,
    uint32_t* __restrict__ w1p16, uint32_t* __restrict__ w2a,
    uint32_t* __restrict__ w1pk)
{
    int idx = blockIdx.x * 256 + threadIdx.x;
    if (idx < 25600) {                          // FC1 weights, 2 halves per u32
        int o = idx / 400, pos = idx - o * 400;
        int k0 = 2 * pos;
        float v0 = 0.f, v1 = 0.f;
        if (k0 < 784)     v0 = f1w[o * 784 + (k0 & 15) * 49 + (k0 >> 4)];
        if (k0 + 1 < 784) v1 = f1w[o * 784 + ((k0 + 1) & 15) * 49 + ((k0 + 1) >> 4)];
        w1p16[idx] = pk2(v0, v1);
    } else if (idx < 25600 + 768) {             // conv2 A-operand
        int i = idx - 25600;
        int oc = i / 48, pos = i - oc * 48;
        int k0 = 2 * pos;
        float v0 = (k0 < 72)     ? c2w[oc * 72 + (k0 & 7) * 9 + (k0 >> 3)] : 0.f;
        float v1 = (k0 + 1 < 72) ? c2w[oc * 72 + ((k0 + 1) & 7) * 9 + ((k0 + 1) >> 3)] : 0.f;
        w2a[i] = pk2(v0, v1);
    } else if (idx < 25600 + 768 + 36) {        // conv1 pk weight pairs
        int j = idx - 26368;
        int t = j >> 2, pr = j & 3;
        w1pk[j] = pk2(c1w[(2 * pr) * 9 + t], c1w[(2 * pr + 1) * 9 + t]);
    } else if (idx < 25600 + 768 + 40) {        // conv1 bias pairs
        int pr = idx - 26404;
        w1pk[36 + pr] = pk2(c1b[2 * pr], c1b[2 * pr + 1]);
    }
}

// -----------------------------------------------------------------------------
// Fused CNN. Block = 4 samples, 4 waves.
//   stage0: image -> zero-padded f16 LDS [4][30][32]
//   stage1: conv1+pool+relu via v_pk_fma_f16 -> h1 [4][16][18][8ic] f16 (padded)
//   stage2: conv2 implicit-GEMM MFMA 16x16x32_f16, pool-major N, shfl pooling
//   stage3: FC1 MFMA (M=64, K=800, N=4)
//   stage4: FC2 shuffle-reduce; per-block stats atomicAdd
// -----------------------------------------------------------------------------
__global__ __launch_bounds__(256) void fused_cnn(
    const float* __restrict__ x,        // [B,1,28,28]
    const uint32_t* __restrict__ w1pk,  // conv1 packed pairs + bias
    const float* __restrict__ c2b,      // [16]
    const f16* __restrict__ w2a,        // [16][96]
    const f16* __restrict__ w1p16,      // [64][800]
    const float* __restrict__ f1b,      // [64]
    const float* __restrict__ f2w,      // [4,64]
    const float* __restrict__ f2b,      // [4]
    float* __restrict__ logits,         // [B,4]
    float* __restrict__ stats)          // [8] atomic accumulators
{
    const int tid  = threadIdx.x;
    const int lane = tid & 63;
    const int wid  = tid >> 6;
    const int b0   = blockIdx.x * NS;

    __shared__ __align__(16) f16 h1[NS * 16 * 18 * 8];       // 18432 B
    __shared__ __align__(16) unsigned char uni[7680];        // simg | sfeat+sh+lbuf
    f16*   simg  = (f16*)uni;            // [4][30][32] padded image (stage0/1)
    f16*   sfeat = (f16*)uni;            // [4][800] f16 feats (stage2+)
    float* shl   = (float*)(uni + 6400); // [4][64] fc1 acts
    float* lbuf  = (float*)(uni + 7424); // [16] block logits

    // ---- zero LDS (pad rings must be 0) ------------------------------------
    {
        uint32_t* u = (uint32_t*)uni;
        for (int i = tid; i < 1920; i += 256) u[i] = 0;
        uint32_t* h = (uint32_t*)h1;
        for (int i = tid; i < 4608; i += 256) h[i] = 0;
    }

    // conv1 packed weights -> wave-uniform (SGPR)
    f16x2 wpk[36], bpk[4];
#pragma unroll
    for (int t = 0; t < 36; ++t) wpk[t] = __builtin_bit_cast(f16x2, rfl_u(w1pk[t]));
#pragma unroll
    for (int p = 0; p < 4; ++p) bpk[p] = __builtin_bit_cast(f16x2, rfl_u(w1pk[36 + p]));

    __syncthreads();

    // ---- stage 0: image -> padded f16 LDS ----------------------------------
#pragma unroll 1
    for (int pass = 0; pass < 4; ++pass) {
        int item = pass * 256 + tid;          // (s, float4 index) over 4*196
        if (item < NS * 196) {
            int s = item / 196, i2 = item - s * 196;
            int r = i2 / 7, c4 = i2 - 7 * r;
            float4 v = *(const float4*)(x + (size_t)(b0 + s) * 784 + r * 28 + c4 * 4);
            f16* dst = simg + (s * 30 + r + 1) * 32 + c4 * 4 + 1;
            dst[0] = (f16)v.x; dst[1] = (f16)v.y; dst[2] = (f16)v.z; dst[3] = (f16)v.w;
        }
    }
    __syncthreads();

    // ---- stage 1: conv1 + pool + relu (pk_fma, f16 accum) ------------------
#pragma unroll 1
    for (int pass = 0; pass < 4; ++pass) {
        int item = pass * 256 + tid;          // (s, pooled pix)
        if (item < NS * 196) {
            int s = item / 196, pix = item - s * 196;
            int py = pix / 14, px = pix - 14 * py;
            const f16* ib = simg + (s * 30 + 2 * py) * 32 + 2 * px;
            f16x2 acc[2][2][4];
#pragma unroll
            for (int qy = 0; qy < 2; ++qy)
#pragma unroll
            for (int qx = 0; qx < 2; ++qx)
#pragma unroll
            for (int pr = 0; pr < 4; ++pr) acc[qy][qx][pr] = bpk[pr];

#pragma unroll
            for (int rr = 0; rr < 4; ++rr) {
                f16x2 plo = *(const f16x2*)(ib + rr * 32);
                f16x2 phi = *(const f16x2*)(ib + rr * 32 + 2);
                f16x2 sp[4];
                sp[0][0] = plo[0]; sp[0][1] = plo[0];
                sp[1][0] = plo[1]; sp[1][1] = plo[1];
                sp[2][0] = phi[0]; sp[2][1] = phi[0];
                sp[3][0] = phi[1]; sp[3][1] = phi[1];
#pragma unroll
                for (int qy = 0; qy < 2; ++qy) {
                    int ky = rr - qy;
                    if (ky < 0 || ky > 2) continue;
#pragma unroll
                    for (int qx = 0; qx < 2; ++qx)
#pragma unroll
                    for (int kx = 0; kx < 3; ++kx) {
#pragma unroll
                        for (int pr = 0; pr < 4; ++pr)
                            acc[qy][qx][pr] = __builtin_elementwise_fma(
                                sp[qx + kx], wpk[(ky * 3 + kx) * 4 + pr], acc[qy][qx][pr]);
                    }
                }
            }
            f16x2 z; z[0] = (f16)0.f; z[1] = (f16)0.f;
            uint32_t ov[4];
#pragma unroll
            for (int pr = 0; pr < 4; ++pr) {
                f16x2 m = __builtin_elementwise_max(
                    __builtin_elementwise_max(acc[0][0][pr], acc[0][1][pr]),
                    __builtin_elementwise_max(acc[1][0][pr], acc[1][1][pr]));
                m = __builtin_elementwise_max(m, z);
                ov[pr] = __builtin_bit_cast(uint32_t, m);
            }
            uint4 val = make_uint4(ov[0], ov[1], ov[2], ov[3]);
            *(uint4*)(h1 + ((s * 16 + py + 1) * 18 + (px + 1)) * 8) = val;
        }
    }
    __syncthreads();

    // zero FC1 K-pad region of sfeat (simg is dead now)
    if (tid < 64) sfeat[(tid >> 4) * 800 + 784 + (tid & 15)] = (f16)0.f;

    const int col = lane & 15, grp = lane >> 4;

    // ---- stage 2: conv2 implicit-GEMM MFMA ---------------------------------
    {
        const int s = wid;
        const f16* h1b = h1 + s * (16 * 18 * 8);
        const int q = col & 3, pl = col >> 2;
        const int qy = q >> 1, qx = q & 1;
        int koff[3];
#pragma unroll
        for (int st = 0; st < 3; ++st) {
            int t = st * 4 + grp;
            int ky = (t < 9) ? (t / 3) : 0;
            int kx = (t < 9) ? (t - 3 * (t / 3)) : 0;
            koff[st] = (ky * 18 + kx) * 8;
        }
        f16x8 af[3];
#pragma unroll
        for (int st = 0; st < 3; ++st)
            af[st] = *(const f16x8*)(w2a + col * 96 + st * 32 + grp * 8);
        f32x4 cb;
#pragma unroll
        for (int r = 0; r < 4; ++r) cb[r] = c2b[grp * 4 + r];

#pragma unroll 1
        for (int t = 0; t < 13; ++t) {
            int pc = 4 * t + pl; pc = pc > 48 ? 48 : pc;       // clamp tail tile
            int py = (pc * 9363) >> 16;                        // pc / 7
            int px = pc - 7 * py;
            const f16* bp = h1b + ((2 * py + qy) * 18 + (2 * px + qx)) * 8;
            f32x4 c = cb;
#pragma unroll
            for (int st = 0; st < 3; ++st) {
                f16x8 bv = *(const f16x8*)(bp + koff[st]);
                c = __builtin_amdgcn_mfma_f32_16x16x32_f16(af[st], bv, c, 0, 0, 0);
            }
            float vr[4];
#pragma unroll
            for (int r = 0; r < 4; ++r) {
                float v = c[r];
                v = fmaxf(v, __shfl_xor(v, 1));
                v = fmaxf(v, __shfl_xor(v, 2));
                vr[r] = fmaxf(v, 0.f);
            }
            int p = 4 * t + pl;
            if (q == 0 && p <= 48) {
                uint2 val = make_uint2(pk2(vr[0], vr[1]), pk2(vr[2], vr[3]));
                *(uint2*)(sfeat + s * 800 + p * 16 + grp * 4) = val;
            }
        }
    }
    __syncthreads();

    // ---- stage 3: FC1 via MFMA (M=64 split across waves, N=4) --------------
    {
        const int m = wid;
        const f16* wb = w1p16 + (m * 16 + col) * 800 + grp * 8;
        const int scol = col < NS ? col : 0;                   // clamp B cols
        const f16* fb = sfeat + scol * 800 + grp * 8;
        f32x4 c = {0.f, 0.f, 0.f, 0.f};
#pragma unroll 5
        for (int st = 0; st < 25; ++st) {
            f16x8 a = *(const f16x8*)(wb + st * 32);
            f16x8 b = *(const f16x8*)(fb + st * 32);
            c = __builtin_amdgcn_mfma_f32_16x16x32_f16(a, b, c, 0, 0, 0);
        }
        if (col < NS) {
            float4 h;
            h.x = fmaxf(c[0] + f1b[m * 16 + grp * 4 + 0], 0.f);
            h.y = fmaxf(c[1] + f1b[m * 16 + grp * 4 + 1], 0.f);
            h.z = fmaxf(c[2] + f1b[m * 16 + grp * 4 + 2], 0.f);
            h.w = fmaxf(c[3] + f1b[m * 16 + grp * 4 + 3], 0.f);
            *(float4*)(shl + col * 64 + m * 16 + grp * 4) = h;
        }
    }
    __syncthreads();

    // ---- stage 4: FC2 + logits + block stats -------------------------------
    {
        const int s = wid;
        float hv = shl[s * 64 + lane];
        float lg[4];
#pragma unroll
        for (int o = 0; o < 4; ++o) {
            float pv = hv * f2w[o * 64 + lane];
#pragma unroll
            for (int sft = 32; sft >= 1; sft >>= 1) pv += __shfl_xor(pv, sft);
            lg[o] = pv + f2b[o];
        }
        if (lane == 0) {
#pragma unroll
            for (int o = 0; o < 4; ++o) {
                logits[(size_t)(b0 + s) * 4 + o] = lg[o];
                lbuf[s * 4 + o] = lg[o];
            }
        }
    }
    __syncthreads();
    if (wid == 0 && lane < 16) {
        float v = lbuf[lane];
        float s1 = v, s2 = v * v;
        s1 += __shfl_xor(s1, 4); s1 += __shfl_xor(s1, 8);
        s2 += __shfl_xor(s2, 4); s2 += __shfl_xor(s2, 8);
        if (lane < 4) {
            atomicAdd(stats + lane, s1);
            atomicAdd(stats + 4 + lane, s2);
        }
    }
}

// -----------------------------------------------------------------------------
// Finalize: BN params from accumulated stats + batch-constant 4-qubit sim
// (feature-map RZ on |0000> is a global phase), then apply affine.
// -----------------------------------------------------------------------------
__global__ __launch_bounds__(256) void finalize_apply(
    const float* __restrict__ logits, const float* __restrict__ stats,
    const float* __restrict__ var, const float* __restrict__ gamma,
    const float* __restrict__ beta, float* __restrict__ out)
{
    __shared__ float prm[8];
    if (threadIdx.x == 0) {
        float pr[16], pi[16];
#pragma unroll
        for (int i = 0; i < 16; ++i) { pr[i] = 0.f; pi[i] = 0.f; }
        pr[0] = 1.f;
        for (int q = 0; q < 4; ++q) {
            float a  = var[3 * q], b_ = var[3 * q + 1], c = var[3 * q + 2];
            float ca = cosf(0.5f * a),  sa = sinf(0.5f * a);
            float cb = cosf(0.5f * b_), sb = sinf(0.5f * b_);
            float cc = cosf(0.5f * c),  sc = sinf(0.5f * c);
            float m00r = cb * ca, m00i =  sb * sa;
            float m01r = -sb * ca, m01i = -cb * sa;
            float m10r =  sb * ca, m10i = -cb * sa;
            float m11r =  cb * ca, m11i = -sb * sa;
            float u00r = cc * m00r + sc * m00i, u00i = cc * m00i - sc * m00r;
            float u01r = cc * m01r + sc * m01i, u01i = cc * m01i - sc * m01r;
            float u10r = cc * m10r - sc * m10i, u10i = cc * m10i + sc * m10r;
            float u11r = cc * m11r - sc * m11i, u11i = cc * m11i + sc * m11r;
            int stq = 1 << (3 - q);
            for (int i = 0; i < 16; ++i) {
                if (i & stq) continue;
                int j = i | stq;
                float xr = pr[i], xi = pi[i], yr = pr[j], yi = pi[j];
                pr[i] = u00r * xr - u00i * xi + u01r * yr - u01i * yi;
                pi[i] = u00r * xi + u00i * xr + u01r * yi + u01i * yr;
                pr[j] = u10r * xr - u10i * xi + u11r * yr - u11i * yi;
                pi[j] = u10r * xi + u10i * xr + u11r * yi + u11i * yr;
            }
        }
        for (int c = 0; c < 3; ++c) {
            int scm = 1 << (3 - c), stm = 1 << (2 - c);
            for (int i = 0; i < 16; ++i) {
                if ((i & scm) && !(i & stm)) {
                    int j = i | stm;
                    float tr = pr[i], ti = pi[i];
                    pr[i] = pr[j]; pi[i] = pi[j];
                    pr[j] = tr;    pi[j] = ti;
                }
            }
        }
        float p[16];
#pragma unroll
        for (int i = 0; i < 16; ++i) p[i] = pr[i] * pr[i] + pi[i] * pi[i];
        float e[4];
        for (int k = 0; k < 4; ++k) {
            float s = 0.f;
            for (int i = 0; i < 16; ++i)
                s += ((i >> (3 - k)) & 1) ? -p[i] : p[i];
            e[k] = s;
        }
        const float invB = 1.0f / (float)BATCH;
        for (int j = 0; j < 4; ++j) {
            float mu   = stats[j] * invB;
            float vr   = stats[4 + j] * invB - mu * mu;
            float istd = 1.0f / sqrtf(vr + 1e-5f);
            float scale = gamma[j] * istd;
            prm[j]     = scale;
            prm[4 + j] = beta[j] - mu * scale + e[3 - j];
        }
    }
    __syncthreads();

    const int i = blockIdx.x * 256 + threadIdx.x;
    float4 v = ((const float4*)logits)[i];
    float4 r;
    r.x = v.x * prm[0] + prm[4];
    r.y = v.y * prm[1] + prm[5];
    r.z = v.z * prm[2] + prm[6];
    r.w = v.w * prm[3] + prm[7];
    ((float4*)out)[i] = r;
}

extern "C" void kernel_launch(void* const* d_in, const int* in_sizes, int n_in,
                              void* d_out, int out_size, void* d_ws, size_t ws_size,
                              hipStream_t stream) {
    (void)in_sizes; (void)n_in; (void)out_size; (void)ws_size;
    const float* x   = (const float*)d_in[0];
    const float* c1w = (const float*)d_in[1];
    const float* c1b = (const float*)d_in[2];
    const float* c2w = (const float*)d_in[3];
    const float* c2b = (const float*)d_in[4];
    const float* f1w = (const float*)d_in[5];
    const float* f1b = (const float*)d_in[6];
    const float* f2w = (const float*)d_in[7];
    const float* f2b = (const float*)d_in[8];
    const float* gma = (const float*)d_in[9];
    const float* bta = (const float*)d_in[10];
    const float* var = (const float*)d_in[11];
    float* out = (float*)d_out;

    float*    logits = (float*)d_ws;                 // 131072 B
    float*    stats  = logits + 32768;               // 32 B
    uint32_t* w1p16  = (uint32_t*)(stats + 8);       // 102400 B ([64][800] f16)
    uint32_t* w2a    = w1p16 + 25600;                // 3072 B  ([16][96] f16)
    uint32_t* w1pk   = w2a + 768;                    // 160 B

    hipMemsetAsync(stats, 0, 8 * sizeof(float), stream);
    pack_weights<<<104, 256, 0, stream>>>(f1w, c2w, c1w, c1b, w1p16, w2a, w1pk);
    fused_cnn<<<BATCH / NS, 256, 0, stream>>>(x, w1pk, c2b, (const f16*)w2a,
                                              (const f16*)w1p16, f1b, f2w, f2b,
                                              logits, stats);
    finalize_apply<<<32, 256, 0, stream>>>(logits, stats, var, gma, bta, out);
}

// Round 5
// 149.553 us; speedup vs baseline: 1.3932x; 1.3932x over previous
//
#include <hip/hip_runtime.h>
#include <math.h>
#include <stdint.h>

#define BATCH 8192
#define NS 4

typedef _Float16 f16;
typedef _Float16 f16x2 __attribute__((ext_vector_type(2)));
typedef _Float16 f16x8 __attribute__((ext_vector_type(8)));
typedef float f32x4 __attribute__((ext_vector_type(4)));
typedef uint32_t u32x4 __attribute__((ext_vector_type(4)));

__device__ __forceinline__ uint32_t pk2(float a, float b) {
    return __builtin_bit_cast(uint32_t, __builtin_amdgcn_cvt_pkrtz(a, b));
}
__device__ __forceinline__ uint32_t rfl_u(uint32_t v) {
    return (uint32_t)__builtin_amdgcn_readfirstlane((int)v);
}

// -----------------------------------------------------------------------------
// Fused CNN. Block = 4 samples, 4 waves. 2-dispatch pipeline: all weight
// packing happens per-block (L2-hot, overlaps image loads).
//   stage0: image -> zero-padded f16 LDS [4][30][32]
//   stage1: conv1+pool+relu via v_pk_fma_f16 -> h1 [4][16][18][8ic] f16
//   stage2: conv2 implicit-GEMM MFMA 16x16x32_f16 (A from LDS pack),
//           pool via shfl, feats stored in ORIGINAL order [oc*49+pix]
//   stage3: FC1 MFMA, A = f1w fp32 rows converted on the fly (no repack)
//   stage4: FC2 shuffle-reduce -> logits
// -----------------------------------------------------------------------------
__global__ __launch_bounds__(256) void fused_cnn(
    const float* __restrict__ x,        // [B,1,28,28]
    const float* __restrict__ c1w,      // [8,9]
    const float* __restrict__ c1b,      // [8]
    const float* __restrict__ c2w,      // [16,8,9]
    const float* __restrict__ c2b,      // [16]
    const float* __restrict__ f1w,      // [64,784]
    const float* __restrict__ f1b,      // [64]
    const float* __restrict__ f2w,      // [4,64]
    const float* __restrict__ f2b,      // [4]
    float* __restrict__ logits)         // [B,4]
{
    const int tid  = threadIdx.x;
    const int lane = tid & 63;
    const int wid  = tid >> 6;
    const int b0   = blockIdx.x * NS;

    __shared__ __align__(16) f16 h1[NS * 16 * 18 * 8];       // 18432 B
    __shared__ __align__(16) f16 sw2a[16 * 96];              // 3072 B conv2 A
    __shared__ __align__(16) unsigned char uni[7680];        // simg | sfeat+shl
    f16*   simg  = (f16*)uni;            // [4][30][32] padded image (stage0/1)
    f16*   sfeat = (f16*)uni;            // [4][800] f16 feats, original order
    float* shl   = (float*)(uni + 6400); // [4][64] fc1 acts

    // ---- zero LDS (pad rings must be 0) + pack conv2 A-operand -------------
    {
        uint32_t* u = (uint32_t*)uni;
        for (int i = tid; i < 1920; i += 256) u[i] = 0;
        uint32_t* h = (uint32_t*)h1;
        for (int i = tid; i < 4608; i += 256) h[i] = 0;
        // sw2a[oc][k], k = tap*8 + ic ; k >= 72 -> 0
        for (int i = tid; i < 1536; i += 256) {
            int oc = i / 96, kk = i - oc * 96;
            float v = (kk < 72) ? c2w[oc * 72 + (kk & 7) * 9 + (kk >> 3)] : 0.f;
            sw2a[i] = (f16)v;
        }
    }

    // conv1 packed weights -> SGPR (computed per-wave from uniform loads)
    f16x2 wpk[36], bpk[4];
#pragma unroll
    for (int t = 0; t < 9; ++t)
#pragma unroll
        for (int pr = 0; pr < 4; ++pr)
            wpk[t * 4 + pr] = __builtin_bit_cast(f16x2,
                rfl_u(pk2(c1w[(2 * pr) * 9 + t], c1w[(2 * pr + 1) * 9 + t])));
#pragma unroll
    for (int pr = 0; pr < 4; ++pr)
        bpk[pr] = __builtin_bit_cast(f16x2, rfl_u(pk2(c1b[2 * pr], c1b[2 * pr + 1])));

    __syncthreads();

    // ---- stage 0: image -> padded f16 LDS ----------------------------------
#pragma unroll 1
    for (int pass = 0; pass < 4; ++pass) {
        int item = pass * 256 + tid;          // (s, float4 index) over 4*196
        if (item < NS * 196) {
            int s = item / 196, i2 = item - s * 196;
            int r = i2 / 7, c4 = i2 - 7 * r;
            float4 v = *(const float4*)(x + (size_t)(b0 + s) * 784 + r * 28 + c4 * 4);
            f16* dst = simg + (s * 30 + r + 1) * 32 + c4 * 4 + 1;
            dst[0] = (f16)v.x; dst[1] = (f16)v.y; dst[2] = (f16)v.z; dst[3] = (f16)v.w;
        }
    }
    __syncthreads();

    // ---- stage 1: conv1 + pool + relu (pk_fma, f16 accum) ------------------
#pragma unroll 1
    for (int pass = 0; pass < 4; ++pass) {
        int item = pass * 256 + tid;          // (s, pooled pix)
        if (item < NS * 196) {
            int s = item / 196, pix = item - s * 196;
            int py = pix / 14, px = pix - 14 * py;
            const f16* ib = simg + (s * 30 + 2 * py) * 32 + 2 * px;
            f16x2 acc[2][2][4];
#pragma unroll
            for (int qy = 0; qy < 2; ++qy)
#pragma unroll
            for (int qx = 0; qx < 2; ++qx)
#pragma unroll
            for (int pr = 0; pr < 4; ++pr) acc[qy][qx][pr] = bpk[pr];

#pragma unroll
            for (int rr = 0; rr < 4; ++rr) {
                f16x2 plo = *(const f16x2*)(ib + rr * 32);
                f16x2 phi = *(const f16x2*)(ib + rr * 32 + 2);
                f16x2 sp[4];
                sp[0][0] = plo[0]; sp[0][1] = plo[0];
                sp[1][0] = plo[1]; sp[1][1] = plo[1];
                sp[2][0] = phi[0]; sp[2][1] = phi[0];
                sp[3][0] = phi[1]; sp[3][1] = phi[1];
#pragma unroll
                for (int qy = 0; qy < 2; ++qy) {
                    int ky = rr - qy;
                    if (ky < 0 || ky > 2) continue;
#pragma unroll
                    for (int qx = 0; qx < 2; ++qx)
#pragma unroll
                    for (int kx = 0; kx < 3; ++kx) {
#pragma unroll
                        for (int pr = 0; pr < 4; ++pr)
                            acc[qy][qx][pr] = __builtin_elementwise_fma(
                                sp[qx + kx], wpk[(ky * 3 + kx) * 4 + pr], acc[qy][qx][pr]);
                    }
                }
            }
            f16x2 z; z[0] = (f16)0.f; z[1] = (f16)0.f;
            uint32_t ov[4];
#pragma unroll
            for (int pr = 0; pr < 4; ++pr) {
                f16x2 m = __builtin_elementwise_max(
                    __builtin_elementwise_max(acc[0][0][pr], acc[0][1][pr]),
                    __builtin_elementwise_max(acc[1][0][pr], acc[1][1][pr]));
                m = __builtin_elementwise_max(m, z);
                ov[pr] = __builtin_bit_cast(uint32_t, m);
            }
            uint4 val = make_uint4(ov[0], ov[1], ov[2], ov[3]);
            *(uint4*)(h1 + ((s * 16 + py + 1) * 18 + (px + 1)) * 8) = val;
        }
    }
    __syncthreads();

    // zero FC1 K-pad region of sfeat (simg is dead now)
    if (tid < 64) sfeat[(tid >> 4) * 800 + 784 + (tid & 15)] = (f16)0.f;

    const int col = lane & 15, grp = lane >> 4;

    // ---- stage 2: conv2 implicit-GEMM MFMA ---------------------------------
    {
        const int s = wid;
        const f16* h1b = h1 + s * (16 * 18 * 8);
        const int q = col & 3, pl = col >> 2;
        const int qy = q >> 1, qx = q & 1;
        int koff[3];
#pragma unroll
        for (int st = 0; st < 3; ++st) {
            int t = st * 4 + grp;
            int ky = (t < 9) ? (t / 3) : 0;
            int kx = (t < 9) ? (t - 3 * (t / 3)) : 0;
            koff[st] = (ky * 18 + kx) * 8;
        }
        f16x8 af[3];
#pragma unroll
        for (int st = 0; st < 3; ++st)
            af[st] = *(const f16x8*)(sw2a + col * 96 + st * 32 + grp * 8);
        f32x4 cb;
#pragma unroll
        for (int r = 0; r < 4; ++r) cb[r] = c2b[grp * 4 + r];

#pragma unroll 1
        for (int t = 0; t < 13; ++t) {
            int pc = 4 * t + pl; pc = pc > 48 ? 48 : pc;       // clamp tail tile
            int py = (pc * 9363) >> 16;                        // pc / 7
            int px = pc - 7 * py;
            const f16* bp = h1b + ((2 * py + qy) * 18 + (2 * px + qx)) * 8;
            f32x4 c = cb;
#pragma unroll
            for (int st = 0; st < 3; ++st) {
                f16x8 bv = *(const f16x8*)(bp + koff[st]);
                c = __builtin_amdgcn_mfma_f32_16x16x32_f16(af[st], bv, c, 0, 0, 0);
            }
            float vr[4];
#pragma unroll
            for (int r = 0; r < 4; ++r) {
                float v = c[r];
                v = fmaxf(v, __shfl_xor(v, 1));
                v = fmaxf(v, __shfl_xor(v, 2));
                vr[r] = fmaxf(v, 0.f);
            }
            int p = 4 * t + pl;
            if (q == 0 && p <= 48) {
#pragma unroll
                for (int r = 0; r < 4; ++r)
                    sfeat[s * 800 + (grp * 4 + r) * 49 + p] = (f16)vr[r];
            }
        }
    }
    __syncthreads();

    // ---- stage 3: FC1 via MFMA, A converted from fp32 f1w on the fly -------
    {
        const int row = wid * 16 + col;                       // output unit
        const float* wrow = f1w + (size_t)row * 784;
        const int scol = col < NS ? col : 0;                  // clamp B cols
        const f16* fb = sfeat + scol * 800;
        f32x4 c = {0.f, 0.f, 0.f, 0.f};
#pragma unroll 5
        for (int st = 0; st < 25; ++st) {
            int k0 = st * 32 + grp * 8;
            f16x8 a;
            if (k0 < 784) {
                float4 lo = *(const float4*)(wrow + k0);
                float4 hi = *(const float4*)(wrow + k0 + 4);
                u32x4 t = { pk2(lo.x, lo.y), pk2(lo.z, lo.w),
                            pk2(hi.x, hi.y), pk2(hi.z, hi.w) };
                a = __builtin_bit_cast(f16x8, t);
            } else {
                u32x4 t = {0u, 0u, 0u, 0u};
                a = __builtin_bit_cast(f16x8, t);
            }
            f16x8 b = *(const f16x8*)(fb + k0);
            c = __builtin_amdgcn_mfma_f32_16x16x32_f16(a, b, c, 0, 0, 0);
        }
        if (col < NS) {
            float4 h;
            h.x = fmaxf(c[0] + f1b[wid * 16 + grp * 4 + 0], 0.f);
            h.y = fmaxf(c[1] + f1b[wid * 16 + grp * 4 + 1], 0.f);
            h.z = fmaxf(c[2] + f1b[wid * 16 + grp * 4 + 2], 0.f);
            h.w = fmaxf(c[3] + f1b[wid * 16 + grp * 4 + 3], 0.f);
            *(float4*)(shl + col * 64 + wid * 16 + grp * 4) = h;
        }
    }
    __syncthreads();

    // ---- stage 4: FC2 (64->4) + logits -------------------------------------
    {
        const int s = wid;
        float hv = shl[s * 64 + lane];
        float lg[4];
#pragma unroll
        for (int o = 0; o < 4; ++o) {
            float pv = hv * f2w[o * 64 + lane];
#pragma unroll
            for (int sft = 32; sft >= 1; sft >>= 1) pv += __shfl_xor(pv, sft);
            lg[o] = pv + f2b[o];
        }
        if (lane == 0) {
#pragma unroll
            for (int o = 0; o < 4; ++o)
                logits[(size_t)(b0 + s) * 4 + o] = lg[o];
        }
    }
}

// -----------------------------------------------------------------------------
// Tail: each of 32 blocks redundantly reduces all logits -> BN stats; thread 0
// runs the (batch-constant) 4-qubit sim; block applies affine to its slice.
// -----------------------------------------------------------------------------
__global__ __launch_bounds__(256) void stats_apply(
    const float* __restrict__ logits, const float* __restrict__ var,
    const float* __restrict__ gamma, const float* __restrict__ beta,
    float* __restrict__ out)
{
    const int tid = threadIdx.x;
    const float4* l4 = (const float4*)logits;

    float t[8] = {0, 0, 0, 0, 0, 0, 0, 0};
#pragma unroll 4
    for (int i = 0; i < 32; ++i) {
        float4 v = l4[tid + 256 * i];
        t[0] += v.x; t[1] += v.y; t[2] += v.z; t[3] += v.w;
        t[4] += v.x * v.x; t[5] += v.y * v.y; t[6] += v.z * v.z; t[7] += v.w * v.w;
    }
#pragma unroll
    for (int sft = 32; sft >= 1; sft >>= 1)
#pragma unroll
        for (int j = 0; j < 8; ++j) t[j] += __shfl_xor(t[j], sft);

    __shared__ float part[4][8];
    __shared__ float prm[8];
    if ((tid & 63) == 0) {
#pragma unroll
        for (int j = 0; j < 8; ++j) part[tid >> 6][j] = t[j];
    }
    __syncthreads();

    if (tid == 0) {
        float sums[8];
#pragma unroll
        for (int j = 0; j < 8; ++j)
            sums[j] = part[0][j] + part[1][j] + part[2][j] + part[3][j];

        // 4-qubit statevector sim (ansatz + CNOT chain; feature-map RZ on
        // |0000> is a global phase -> batch-constant expectations)
        float pr[16], pi[16];
#pragma unroll
        for (int i = 0; i < 16; ++i) { pr[i] = 0.f; pi[i] = 0.f; }
        pr[0] = 1.f;
        for (int q = 0; q < 4; ++q) {
            float a  = var[3 * q], b_ = var[3 * q + 1], c = var[3 * q + 2];
            float ca = cosf(0.5f * a),  sa = sinf(0.5f * a);
            float cb = cosf(0.5f * b_), sb = sinf(0.5f * b_);
            float cc = cosf(0.5f * c),  sc = sinf(0.5f * c);
            float m00r = cb * ca, m00i =  sb * sa;
            float m01r = -sb * ca, m01i = -cb * sa;
            float m10r =  sb * ca, m10i = -cb * sa;
            float m11r =  cb * ca, m11i = -sb * sa;
            float u00r = cc * m00r + sc * m00i, u00i = cc * m00i - sc * m00r;
            float u01r = cc * m01r + sc * m01i, u01i = cc * m01i - sc * m01r;
            float u10r = cc * m10r - sc * m10i, u10i = cc * m10i + sc * m10r;
            float u11r = cc * m11r - sc * m11i, u11i = cc * m11i + sc * m11r;
            int stq = 1 << (3 - q);
            for (int i = 0; i < 16; ++i) {
                if (i & stq) continue;
                int j = i | stq;
                float xr = pr[i], xi = pi[i], yr = pr[j], yi = pi[j];
                pr[i] = u00r * xr - u00i * xi + u01r * yr - u01i * yi;
                pi[i] = u00r * xi + u00i * xr + u01r * yi + u01i * yr;
                pr[j] = u10r * xr - u10i * xi + u11r * yr - u11i * yi;
                pi[j] = u10r * xi + u10i * xr + u11r * yi + u11i * yr;
            }
        }
        for (int c = 0; c < 3; ++c) {
            int scm = 1 << (3 - c), stm = 1 << (2 - c);
            for (int i = 0; i < 16; ++i) {
                if ((i & scm) && !(i & stm)) {
                    int j = i | stm;
                    float tr = pr[i], ti = pi[i];
                    pr[i] = pr[j]; pi[i] = pi[j];
                    pr[j] = tr;    pi[j] = ti;
                }
            }
        }
        float p[16];
#pragma unroll
        for (int i = 0; i < 16; ++i) p[i] = pr[i] * pr[i] + pi[i] * pi[i];
        float e[4];
        for (int k = 0; k < 4; ++k) {
            float s = 0.f;
            for (int i = 0; i < 16; ++i)
                s += ((i >> (3 - k)) & 1) ? -p[i] : p[i];
            e[k] = s;
        }
        const float invB = 1.0f / (float)BATCH;
        for (int j = 0; j < 4; ++j) {
            float mu   = sums[j] * invB;
            float vr   = sums[4 + j] * invB - mu * mu;
            float istd = 1.0f / sqrtf(vr + 1e-5f);
            float scale = gamma[j] * istd;
            prm[j]     = scale;
            prm[4 + j] = beta[j] - mu * scale + e[3 - j];
        }
    }
    __syncthreads();

    const int smp = blockIdx.x * 256 + tid;
    float4 v = l4[smp];
    float4 r;
    r.x = v.x * prm[0] + prm[4];
    r.y = v.y * prm[1] + prm[5];
    r.z = v.z * prm[2] + prm[6];
    r.w = v.w * prm[3] + prm[7];
    ((float4*)out)[smp] = r;
}

extern "C" void kernel_launch(void* const* d_in, const int* in_sizes, int n_in,
                              void* d_out, int out_size, void* d_ws, size_t ws_size,
                              hipStream_t stream) {
    (void)in_sizes; (void)n_in; (void)out_size; (void)ws_size;
    const float* x   = (const float*)d_in[0];
    const float* c1w = (const float*)d_in[1];
    const float* c1b = (const float*)d_in[2];
    const float* c2w = (const float*)d_in[3];
    const float* c2b = (const float*)d_in[4];
    const float* f1w = (const float*)d_in[5];
    const float* f1b = (const float*)d_in[6];
    const float* f2w = (const float*)d_in[7];
    const float* f2b = (const float*)d_in[8];
    const float* gma = (const float*)d_in[9];
    const float* bta = (const float*)d_in[10];
    const float* var = (const float*)d_in[11];
    float* out = (float*)d_out;

    float* logits = (float*)d_ws;                 // 131072 B

    fused_cnn<<<BATCH / NS, 256, 0, stream>>>(x, c1w, c1b, c2w, c2b,
                                              f1w, f1b, f2w, f2b, logits);
    stats_apply<<<32, 256, 0, stream>>>(logits, var, gma, bta, out);
}

// Round 6
// 146.694 us; speedup vs baseline: 1.4203x; 1.0195x over previous
//
#include <hip/hip_runtime.h>
#include <math.h>
#include <stdint.h>

#define BATCH 8192
#define NS 8            // samples per block = waves per block

typedef _Float16 f16;
typedef _Float16 f16x2 __attribute__((ext_vector_type(2)));
typedef _Float16 f16x8 __attribute__((ext_vector_type(8)));
typedef float f32x4 __attribute__((ext_vector_type(4)));
typedef uint32_t u32x4 __attribute__((ext_vector_type(4)));

__device__ __forceinline__ uint32_t pk2(float a, float b) {
    return __builtin_bit_cast(uint32_t, __builtin_amdgcn_cvt_pkrtz(a, b));
}
__device__ __forceinline__ uint32_t rfl_u(uint32_t v) {
    return (uint32_t)__builtin_amdgcn_readfirstlane((int)v);
}
__device__ __forceinline__ void wave_lds_fence() {
    // per-wave LDS ordering: DS ops are in-order per wave; this pins the
    // compiler from reordering subsequent ds_reads before prior ds_writes.
    asm volatile("s_waitcnt lgkmcnt(0)" ::: "memory");
}

// -----------------------------------------------------------------------------
// Fused CNN. Block = 8 samples, 8 waves (512 thr). Wave s owns sample s through
// stages 0-2 (no barriers: wave-private LDS regions, in-order DS pipe). Then:
//   B1 -> FC1 MFMA (4 M-tiles x 2-way split-K, all 8 N-cols used)
//   B2 -> combine split-K partials + bias + relu
//   B3 -> FC2 shuffle-reduce -> logits
// LDS 52224 B -> 3 blocks/CU.
// -----------------------------------------------------------------------------
__global__ __launch_bounds__(512) void fused_cnn(
    const float* __restrict__ x,        // [B,1,28,28]
    const float* __restrict__ c1w,      // [8,9]
    const float* __restrict__ c1b,      // [8]
    const float* __restrict__ c2w,      // [16,8,9]
    const float* __restrict__ c2b,      // [16]
    const float* __restrict__ f1w,      // [64,784]
    const float* __restrict__ f1b,      // [64]
    const float* __restrict__ f2w,      // [4,64]
    const float* __restrict__ f2b,      // [4]
    float* __restrict__ logits)         // [B,4]
{
    const int tid  = threadIdx.x;
    const int lane = tid & 63;
    const int wid  = tid >> 6;          // wave = sample 0..7
    const int b0   = blockIdx.x * NS;

    __shared__ __align__(16) f16 h1[NS * 16 * 18 * 8];      // 36864 B
    __shared__ __align__(16) unsigned char uni[NS * 1920];  // 15360 B
    // overlays:
    //   stage0/1: simg[s] = uni + s*1920      ([30][32] f16, zero-padded)
    //   stage2+ : sfeat[s] = (f16*)uni + s*968 (968 = 960 + s-skew 8 for banks;
    //             max use 968*7+808 < 7680 f16 = 15360 B, each within own slot)
    //   FC1+    : part = (float*)h1 (4096 B), shl = (float*)(h1+2048 f16) (2048 B)
    float* part = (float*)h1;
    float* shl  = (float*)((unsigned char*)h1 + 4096);

    // ---- per-wave zero of own simg + h1 regions ----------------------------
    {
        uint4 z = make_uint4(0, 0, 0, 0);
        uint4* zs = (uint4*)(uni + wid * 1920);
        for (int i = lane; i < 120; i += 64) zs[i] = z;
        uint4* zh = (uint4*)(h1 + wid * 2304);
        for (int i = lane; i < 288; i += 64) zh[i] = z;
    }

    // conv1 packed weights -> SGPR (wave-uniform)
    f16x2 wpk[36], bpk[4];
#pragma unroll
    for (int t = 0; t < 9; ++t)
#pragma unroll
        for (int pr = 0; pr < 4; ++pr)
            wpk[t * 4 + pr] = __builtin_bit_cast(f16x2,
                rfl_u(pk2(c1w[(2 * pr) * 9 + t], c1w[(2 * pr + 1) * 9 + t])));
#pragma unroll
    for (int pr = 0; pr < 4; ++pr)
        bpk[pr] = __builtin_bit_cast(f16x2, rfl_u(pk2(c1b[2 * pr], c1b[2 * pr + 1])));

    const int col = lane & 15, grp = lane >> 4;

    // conv2 A-fragment gathered straight from global (L1/L2-hot, once per wave)
    f16x8 af[3];
#pragma unroll
    for (int st = 0; st < 3; ++st) {
        int tap = st * 4 + grp;
        if (tap < 9) {
            float tmp[8];
#pragma unroll
            for (int j = 0; j < 8; ++j) tmp[j] = c2w[(col * 8 + j) * 9 + tap];
            u32x4 t = { pk2(tmp[0], tmp[1]), pk2(tmp[2], tmp[3]),
                        pk2(tmp[4], tmp[5]), pk2(tmp[6], tmp[7]) };
            af[st] = __builtin_bit_cast(f16x8, t);
        } else {
            u32x4 t = {0u, 0u, 0u, 0u};
            af[st] = __builtin_bit_cast(f16x8, t);
        }
    }

    // ---- stage 0: own image -> padded f16 LDS ------------------------------
    {
        f16* simg = (f16*)(uni + wid * 1920);
        const float* xb = x + (size_t)(b0 + wid) * 784;
        wave_lds_fence();   // zeros complete before interior overwrite ordering
#pragma unroll 1
        for (int pass = 0; pass < 4; ++pass) {
            int item = pass * 64 + lane;      // float4 index over 196
            if (item < 196) {
                int r = item / 7, c4 = item - 7 * r;
                float4 v = *(const float4*)(xb + r * 28 + c4 * 4);
                f16* dst = simg + (r + 1) * 32 + c4 * 4 + 1;
                dst[0] = (f16)v.x; dst[1] = (f16)v.y;
                dst[2] = (f16)v.z; dst[3] = (f16)v.w;
            }
        }
    }
    wave_lds_fence();

    // ---- stage 1: conv1 + pool + relu (pk_fma, f16 accum) ------------------
    {
        const f16* simg = (const f16*)(uni + wid * 1920);
        f16* h1s = h1 + wid * 2304;
#pragma unroll 1
        for (int pass = 0; pass < 4; ++pass) {
            int pix = pass * 64 + lane;       // pooled pixel over 196
            if (pix < 196) {
                int py = pix / 14, px = pix - 14 * py;
                const f16* ib = simg + (2 * py) * 32 + 2 * px;
                f16x2 acc[2][2][4];
#pragma unroll
                for (int qy = 0; qy < 2; ++qy)
#pragma unroll
                for (int qx = 0; qx < 2; ++qx)
#pragma unroll
                for (int pr = 0; pr < 4; ++pr) acc[qy][qx][pr] = bpk[pr];

#pragma unroll
                for (int rr = 0; rr < 4; ++rr) {
                    f16x2 plo = *(const f16x2*)(ib + rr * 32);
                    f16x2 phi = *(const f16x2*)(ib + rr * 32 + 2);
                    f16x2 sp[4];
                    sp[0][0] = plo[0]; sp[0][1] = plo[0];
                    sp[1][0] = plo[1]; sp[1][1] = plo[1];
                    sp[2][0] = phi[0]; sp[2][1] = phi[0];
                    sp[3][0] = phi[1]; sp[3][1] = phi[1];
#pragma unroll
                    for (int qy = 0; qy < 2; ++qy) {
                        int ky = rr - qy;
                        if (ky < 0 || ky > 2) continue;
#pragma unroll
                        for (int qx = 0; qx < 2; ++qx)
#pragma unroll
                        for (int kx = 0; kx < 3; ++kx) {
#pragma unroll
                            for (int pr = 0; pr < 4; ++pr)
                                acc[qy][qx][pr] = __builtin_elementwise_fma(
                                    sp[qx + kx], wpk[(ky * 3 + kx) * 4 + pr],
                                    acc[qy][qx][pr]);
                        }
                    }
                }
                f16x2 z; z[0] = (f16)0.f; z[1] = (f16)0.f;
                uint32_t ov[4];
#pragma unroll
                for (int pr = 0; pr < 4; ++pr) {
                    f16x2 m = __builtin_elementwise_max(
                        __builtin_elementwise_max(acc[0][0][pr], acc[0][1][pr]),
                        __builtin_elementwise_max(acc[1][0][pr], acc[1][1][pr]));
                    m = __builtin_elementwise_max(m, z);
                    ov[pr] = __builtin_bit_cast(uint32_t, m);
                }
                uint4 val = make_uint4(ov[0], ov[1], ov[2], ov[3]);
                *(uint4*)(h1s + ((py + 1) * 18 + (px + 1)) * 8) = val;
            }
        }
    }
    wave_lds_fence();

    // ---- stage 2: conv2 implicit-GEMM MFMA (own sample) --------------------
    {
        const f16* h1b = h1 + wid * 2304;
        f16* sfeats = (f16*)uni + wid * 968;
        const int q = col & 3, pl = col >> 2;
        const int qy = q >> 1, qx = q & 1;
        int koff[3];
#pragma unroll
        for (int st = 0; st < 3; ++st) {
            int t = st * 4 + grp;
            int ky = (t < 9) ? (t / 3) : 0;
            int kx = (t < 9) ? (t - 3 * (t / 3)) : 0;
            koff[st] = (ky * 18 + kx) * 8;
        }
        f32x4 cb;
#pragma unroll
        for (int r = 0; r < 4; ++r) cb[r] = c2b[grp * 4 + r];

#pragma unroll 1
        for (int t = 0; t < 13; ++t) {
            int pc = 4 * t + pl; pc = pc > 48 ? 48 : pc;       // clamp tail
            int py = (pc * 9363) >> 16;                        // pc / 7
            int px = pc - 7 * py;
            const f16* bp = h1b + ((2 * py + qy) * 18 + (2 * px + qx)) * 8;
            f32x4 c = cb;
#pragma unroll
            for (int st = 0; st < 3; ++st) {
                f16x8 bv = *(const f16x8*)(bp + koff[st]);
                c = __builtin_amdgcn_mfma_f32_16x16x32_f16(af[st], bv, c, 0, 0, 0);
            }
            float vr[4];
#pragma unroll
            for (int r = 0; r < 4; ++r) {
                float v = c[r];
                v = fmaxf(v, __shfl_xor(v, 1));
                v = fmaxf(v, __shfl_xor(v, 2));
                vr[r] = fmaxf(v, 0.f);
            }
            int p = 4 * t + pl;
            if (q == 0 && p <= 48) {
#pragma unroll
                for (int r = 0; r < 4; ++r)
                    sfeats[(grp * 4 + r) * 49 + p] = (f16)vr[r];
            }
        }
        // keep FC1's over-read region finite (A is zero there anyway)
        if (lane < 8) *(uint32_t*)(sfeats + 784 + lane * 2) = 0u;
    }
    __syncthreads();                                          // B1

    // ---- stage 3: FC1 via MFMA, 4 M-tiles x 2-way split-K ------------------
    {
        const int rt = wid & 3, kh = wid >> 2;
        const int row = rt * 16 + col;                        // output unit
        const float* wrow = f1w + (size_t)row * 784;
        const int kbase = kh * 416;
        const int steps = 13 - kh;                            // 13 or 12
        const int scol = col < NS ? col : 0;                  // clamp B cols
        const f16* fb = (const f16*)uni + scol * 968;
        f32x4 c = {0.f, 0.f, 0.f, 0.f};
#pragma unroll 4
        for (int st = 0; st < steps; ++st) {
            int k0 = kbase + st * 32 + grp * 8;
            f16x8 a;
            if (k0 < 784) {
                float4 lo = *(const float4*)(wrow + k0);
                float4 hi = *(const float4*)(wrow + k0 + 4);
                u32x4 t = { pk2(lo.x, lo.y), pk2(lo.z, lo.w),
                            pk2(hi.x, hi.y), pk2(hi.z, hi.w) };
                a = __builtin_bit_cast(f16x8, t);
            } else {
                u32x4 t = {0u, 0u, 0u, 0u};
                a = __builtin_bit_cast(f16x8, t);
            }
            f16x8 b = *(const f16x8*)(fb + k0);
            c = __builtin_amdgcn_mfma_f32_16x16x32_f16(a, b, c, 0, 0, 0);
        }
        if (col < NS) {
#pragma unroll
            for (int r = 0; r < 4; ++r)
                part[kh * 512 + (rt * 16 + grp * 4 + r) * 8 + col] = c[r];
        }
    }
    __syncthreads();                                          // B2

    // ---- combine split-K + bias + relu -------------------------------------
    {
        const int m = tid >> 3, sm = tid & 7;
        float v = part[m * 8 + sm] + part[512 + m * 8 + sm] + f1b[m];
        shl[sm * 64 + m] = fmaxf(v, 0.f);
    }
    __syncthreads();                                          // B3

    // ---- stage 4: FC2 (64->4), wave s = sample s ---------------------------
    {
        float hv = shl[wid * 64 + lane];
        float lg[4];
#pragma unroll
        for (int o = 0; o < 4; ++o) {
            float pv = hv * f2w[o * 64 + lane];
#pragma unroll
            for (int sft = 32; sft >= 1; sft >>= 1) pv += __shfl_xor(pv, sft);
            lg[o] = pv + f2b[o];
        }
        if (lane == 0) {
            float4 out4 = make_float4(lg[0], lg[1], lg[2], lg[3]);
            *(float4*)(logits + (size_t)(b0 + wid) * 4) = out4;
        }
    }
}

// -----------------------------------------------------------------------------
// Tail: each of 32 blocks redundantly reduces all logits -> BN stats; thread 0
// runs the (batch-constant) 4-qubit sim; block applies affine to its slice.
// -----------------------------------------------------------------------------
__global__ __launch_bounds__(256) void stats_apply(
    const float* __restrict__ logits, const float* __restrict__ var,
    const float* __restrict__ gamma, const float* __restrict__ beta,
    float* __restrict__ out)
{
    const int tid = threadIdx.x;
    const float4* l4 = (const float4*)logits;

    float t[8] = {0, 0, 0, 0, 0, 0, 0, 0};
#pragma unroll 4
    for (int i = 0; i < 32; ++i) {
        float4 v = l4[tid + 256 * i];
        t[0] += v.x; t[1] += v.y; t[2] += v.z; t[3] += v.w;
        t[4] += v.x * v.x; t[5] += v.y * v.y; t[6] += v.z * v.z; t[7] += v.w * v.w;
    }
#pragma unroll
    for (int sft = 32; sft >= 1; sft >>= 1)
#pragma unroll
        for (int j = 0; j < 8; ++j) t[j] += __shfl_xor(t[j], sft);

    __shared__ float part[4][8];
    __shared__ float prm[8];
    if ((tid & 63) == 0) {
#pragma unroll
        for (int j = 0; j < 8; ++j) part[tid >> 6][j] = t[j];
    }
    __syncthreads();

    if (tid == 0) {
        float sums[8];
#pragma unroll
        for (int j = 0; j < 8; ++j)
            sums[j] = part[0][j] + part[1][j] + part[2][j] + part[3][j];

        // 4-qubit statevector sim (ansatz + CNOT chain; feature-map RZ on
        // |0000> is a global phase -> batch-constant expectations)
        float pr[16], pi[16];
#pragma unroll
        for (int i = 0; i < 16; ++i) { pr[i] = 0.f; pi[i] = 0.f; }
        pr[0] = 1.f;
        for (int q = 0; q < 4; ++q) {
            float a  = var[3 * q], b_ = var[3 * q + 1], c = var[3 * q + 2];
            float ca = cosf(0.5f * a),  sa = sinf(0.5f * a);
            float cb = cosf(0.5f * b_), sb = sinf(0.5f * b_);
            float cc = cosf(0.5f * c),  sc = sinf(0.5f * c);
            float m00r = cb * ca, m00i =  sb * sa;
            float m01r = -sb * ca, m01i = -cb * sa;
            float m10r =  sb * ca, m10i = -cb * sa;
            float m11r =  cb * ca, m11i = -sb * sa;
            float u00r = cc * m00r + sc * m00i, u00i = cc * m00i - sc * m00r;
            float u01r = cc * m01r + sc * m01i, u01i = cc * m01i - sc * m01r;
            float u10r = cc * m10r - sc * m10i, u10i = cc * m10i + sc * m10r;
            float u11r = cc * m11r - sc * m11i, u11i = cc * m11i + sc * m11r;
            int stq = 1 << (3 - q);
            for (int i = 0; i < 16; ++i) {
                if (i & stq) continue;
                int j = i | stq;
                float xr = pr[i], xi = pi[i], yr = pr[j], yi = pi[j];
                pr[i] = u00r * xr - u00i * xi + u01r * yr - u01i * yi;
                pi[i] = u00r * xi + u00i * xr + u01r * yi + u01i * yr;
                pr[j] = u10r * xr - u10i * xi + u11r * yr - u11i * yi;
                pi[j] = u10r * xi + u10i * xr + u11r * yi + u11i * yr;
            }
        }
        for (int c = 0; c < 3; ++c) {
            int scm = 1 << (3 - c), stm = 1 << (2 - c);
            for (int i = 0; i < 16; ++i) {
                if ((i & scm) && !(i & stm)) {
                    int j = i | stm;
                    float tr = pr[i], ti = pi[i];
                    pr[i] = pr[j]; pi[i] = pi[j];
                    pr[j] = tr;    pi[j] = ti;
                }
            }
        }
        float p[16];
#pragma unroll
        for (int i = 0; i < 16; ++i) p[i] = pr[i] * pr[i] + pi[i] * pi[i];
        float e[4];
        for (int k = 0; k < 4; ++k) {
            float s = 0.f;
            for (int i = 0; i < 16; ++i)
                s += ((i >> (3 - k)) & 1) ? -p[i] : p[i];
            e[k] = s;
        }
        const float invB = 1.0f / (float)BATCH;
        for (int j = 0; j < 4; ++j) {
            float mu   = sums[j] * invB;
            float vr   = sums[4 + j] * invB - mu * mu;
            float istd = 1.0f / sqrtf(vr + 1e-5f);
            float scale = gamma[j] * istd;
            prm[j]     = scale;
            prm[4 + j] = beta[j] - mu * scale + e[3 - j];
        }
    }
    __syncthreads();

    const int smp = blockIdx.x * 256 + tid;
    float4 v = l4[smp];
    float4 r;
    r.x = v.x * prm[0] + prm[4];
    r.y = v.y * prm[1] + prm[5];
    r.z = v.z * prm[2] + prm[6];
    r.w = v.w * prm[3] + prm[7];
    ((float4*)out)[smp] = r;
}

extern "C" void kernel_launch(void* const* d_in, const int* in_sizes, int n_in,
                              void* d_out, int out_size, void* d_ws, size_t ws_size,
                              hipStream_t stream) {
    (void)in_sizes; (void)n_in; (void)out_size; (void)ws_size;
    const float* x   = (const float*)d_in[0];
    const float* c1w = (const float*)d_in[1];
    const float* c1b = (const float*)d_in[2];
    const float* c2w = (const float*)d_in[3];
    const float* c2b = (const float*)d_in[4];
    const float* f1w = (const float*)d_in[5];
    const float* f1b = (const float*)d_in[6];
    const float* f2w = (const float*)d_in[7];
    const float* f2b = (const float*)d_in[8];
    const float* gma = (const float*)d_in[9];
    const float* bta = (const float*)d_in[10];
    const float* var = (const float*)d_in[11];
    float* out = (float*)d_out;

    float* logits = (float*)d_ws;                 // 131072 B

    fused_cnn<<<BATCH / NS, 512, 0, stream>>>(x, c1w, c1b, c2w, c2b,
                                              f1w, f1b, f2w, f2b, logits);
    stats_apply<<<32, 256, 0, stream>>>(logits, var, gma, bta, out);
}

// Round 7
// 138.993 us; speedup vs baseline: 1.4990x; 1.0554x over previous
//
#include <hip/hip_runtime.h>
#include <math.h>
#include <stdint.h>

#define BATCH 8192
#define NS 4            // samples per block = waves per block

typedef _Float16 f16;
typedef _Float16 f16x2 __attribute__((ext_vector_type(2)));
typedef _Float16 f16x8 __attribute__((ext_vector_type(8)));
typedef float f32x4 __attribute__((ext_vector_type(4)));
typedef uint32_t u32x4 __attribute__((ext_vector_type(4)));

__device__ __forceinline__ uint32_t pk2(float a, float b) {
    return __builtin_bit_cast(uint32_t, __builtin_amdgcn_cvt_pkrtz(a, b));
}
__device__ __forceinline__ uint32_t rfl_u(uint32_t v) {
    return (uint32_t)__builtin_amdgcn_readfirstlane((int)v);
}
__device__ __forceinline__ void wave_lds_fence() {
    asm volatile("s_waitcnt lgkmcnt(0)" ::: "memory");
}

// -----------------------------------------------------------------------------
// Pack: f1w fp32 [64][784] -> f16 [64][800] (K-pad zeros), original k order.
// -----------------------------------------------------------------------------
__global__ __launch_bounds__(256) void pack_weights(
    const float* __restrict__ f1w, uint32_t* __restrict__ w1p16)
{
    int idx = blockIdx.x * 256 + threadIdx.x;
    if (idx < 25600) {
        int o = idx / 400, pos = idx - o * 400;
        int k0 = 2 * pos;
        float v0 = (k0 < 784)     ? f1w[o * 784 + k0]     : 0.f;
        float v1 = (k0 + 1 < 784) ? f1w[o * 784 + k0 + 1] : 0.f;
        w1p16[idx] = pk2(v0, v1);
    }
}

// -----------------------------------------------------------------------------
// Fused CNN. Block = 4 samples, 4 waves (256 thr). Wave s owns sample s through
// stages 0-2 (wave-private LDS, in-order DS pipe, no barriers). Then:
//   B1 -> FC1 MFMA (wave = 16 output units, K=800, B cols = 4 samples)
//   B2 -> FC2 shuffle-reduce -> logits
// LDS 26624 B -> 6 blocks/CU (75% occupancy).
// -----------------------------------------------------------------------------
__global__ __launch_bounds__(256, 6) void fused_cnn(
    const float* __restrict__ x,        // [B,1,28,28]
    const float* __restrict__ c1w,      // [8,9]
    const float* __restrict__ c1b,      // [8]
    const float* __restrict__ c2w,      // [16,8,9]
    const float* __restrict__ c2b,      // [16]
    const f16* __restrict__ w1p16,      // [64][800] f16 packed
    const float* __restrict__ f1b,      // [64]
    const float* __restrict__ f2w,      // [4,64]
    const float* __restrict__ f2b,      // [4]
    float* __restrict__ logits)         // [B,4]
{
    const int tid  = threadIdx.x;
    const int lane = tid & 63;
    const int wid  = tid >> 6;          // wave = sample 0..3
    const int b0   = blockIdx.x * NS;

    __shared__ __align__(16) f16 h1[NS * 16 * 18 * 8];        // 18432 B
    __shared__ __align__(16) unsigned char uni[NS * 2048];    // 8192 B
    // overlays:
    //   stage0/1: simg[s] = uni + s*2048  : [32 rows][32 cols] f16; image row r
    //             at LDS row r+1, image col c at LDS col c+2 (wrap-pad zeros)
    //   stage2+ : sfeat[s] = same slot     : [800] f16, original order oc*49+p
    //   FC1+    : shl = (float*)h1 ([4][64] fp32), h1 dead after B1
    float* shl = (float*)h1;

    // ---- per-wave zero of own simg + h1 regions ----------------------------
    {
        uint4 z = make_uint4(0, 0, 0, 0);
        uint4* zs = (uint4*)(uni + wid * 2048);
        for (int i = lane; i < 128; i += 64) zs[i] = z;
        uint4* zh = (uint4*)(h1 + wid * 2304);
        for (int i = lane; i < 288; i += 64) zh[i] = z;
    }

    // conv1 packed weights -> SGPR (wave-uniform)
    f16x2 wpk[36], bpk[4];
#pragma unroll
    for (int t = 0; t < 9; ++t)
#pragma unroll
        for (int pr = 0; pr < 4; ++pr)
            wpk[t * 4 + pr] = __builtin_bit_cast(f16x2,
                rfl_u(pk2(c1w[(2 * pr) * 9 + t], c1w[(2 * pr + 1) * 9 + t])));
#pragma unroll
    for (int pr = 0; pr < 4; ++pr)
        bpk[pr] = __builtin_bit_cast(f16x2, rfl_u(pk2(c1b[2 * pr], c1b[2 * pr + 1])));

    const int col = lane & 15, grp = lane >> 4;

    // conv2 A-fragment gathered straight from global (L2-hot, once per wave)
    f16x8 af[3];
    int koff[3];
#pragma unroll
    for (int st = 0; st < 3; ++st) {
        int tap = st * 4 + grp;
        if (tap < 9) {
            int ky = tap / 3, kx = tap - 3 * (tap / 3);
            koff[st] = (ky * 18 + kx) * 8;
            float tmp[8];
#pragma unroll
            for (int j = 0; j < 8; ++j) tmp[j] = c2w[(col * 8 + j) * 9 + tap];
            u32x4 t = { pk2(tmp[0], tmp[1]), pk2(tmp[2], tmp[3]),
                        pk2(tmp[4], tmp[5]), pk2(tmp[6], tmp[7]) };
            af[st] = __builtin_bit_cast(f16x8, t);
        } else {
            koff[st] = 0;
            u32x4 t = {0u, 0u, 0u, 0u};
            af[st] = __builtin_bit_cast(f16x8, t);
        }
    }
    wave_lds_fence();

    // ---- stage 0: own image -> padded f16 LDS (aligned b32 writes) ---------
    {
        f16* simg = (f16*)(uni + wid * 2048);
        const float* xb = x + (size_t)(b0 + wid) * 784;
#pragma unroll 1
        for (int pass = 0; pass < 4; ++pass) {
            int item = pass * 64 + lane;      // float4 index over 196
            if (item < 196) {
                int r = item / 7, c4 = item - 7 * r;
                float4 v = *(const float4*)(xb + r * 28 + c4 * 4);
                int off = (r + 1) * 32 + 2 + 4 * c4;   // 4B-aligned (f16 idx even)
                *(uint32_t*)(simg + off)     = pk2(v.x, v.y);
                *(uint32_t*)(simg + off + 2) = pk2(v.z, v.w);
            }
        }
    }
    wave_lds_fence();

    // ---- stage 1: conv1 + pool + relu (pk_fma, f16 accum) ------------------
    {
        const f16* simg = (const f16*)(uni + wid * 2048);
        f16* h1s = h1 + wid * 2304;
#pragma unroll 1
        for (int pass = 0; pass < 4; ++pass) {
            int pix = pass * 64 + lane;       // pooled pixel over 196
            if (pix < 196) {
                int py = pix / 14, px = pix - 14 * py;
                // read rows u = 2py+rr, aligned f16x2 at LDS cols 2px,2px+2,2px+4
                // (image cols 2px-2 .. 2px+3); P[i] = image col 2px-1+i
                f16x2 acc[2][2][4];
#pragma unroll
                for (int qy = 0; qy < 2; ++qy)
#pragma unroll
                for (int qx = 0; qx < 2; ++qx)
#pragma unroll
                for (int pr = 0; pr < 4; ++pr) acc[qy][qx][pr] = bpk[pr];

#pragma unroll
                for (int rr = 0; rr < 4; ++rr) {
                    const f16* rb = simg + (2 * py + rr) * 32 + 2 * px;
                    f16x2 A = *(const f16x2*)(rb);
                    f16x2 Bv = *(const f16x2*)(rb + 2);
                    f16x2 C = *(const f16x2*)(rb + 4);
                    f16 P[4] = { A[1], Bv[0], Bv[1], C[0] };
                    f16x2 sp[4];
#pragma unroll
                    for (int i = 0; i < 4; ++i) { sp[i][0] = P[i]; sp[i][1] = P[i]; }
#pragma unroll
                    for (int qy = 0; qy < 2; ++qy) {
                        int ky = rr - qy;
                        if (ky < 0 || ky > 2) continue;
#pragma unroll
                        for (int qx = 0; qx < 2; ++qx)
#pragma unroll
                        for (int kx = 0; kx < 3; ++kx) {
#pragma unroll
                            for (int pr = 0; pr < 4; ++pr)
                                acc[qy][qx][pr] = __builtin_elementwise_fma(
                                    sp[qx + kx], wpk[(ky * 3 + kx) * 4 + pr],
                                    acc[qy][qx][pr]);
                        }
                    }
                }
                f16x2 z; z[0] = (f16)0.f; z[1] = (f16)0.f;
                uint32_t ov[4];
#pragma unroll
                for (int pr = 0; pr < 4; ++pr) {
                    f16x2 m = __builtin_elementwise_max(
                        __builtin_elementwise_max(acc[0][0][pr], acc[0][1][pr]),
                        __builtin_elementwise_max(acc[1][0][pr], acc[1][1][pr]));
                    m = __builtin_elementwise_max(m, z);
                    ov[pr] = __builtin_bit_cast(uint32_t, m);
                }
                uint4 val = make_uint4(ov[0], ov[1], ov[2], ov[3]);
                *(uint4*)(h1s + ((py + 1) * 18 + (px + 1)) * 8) = val;
            }
        }
    }
    wave_lds_fence();

    // ---- stage 2: conv2 MFMA, N = 16 pooled pixels, pool-in-registers ------
    {
        const f16* h1b = h1 + wid * 2304;
        f16* sfeats = (f16*)(uni + wid * 2048);
        f32x4 cb;
#pragma unroll
        for (int r = 0; r < 4; ++r) cb[r] = c2b[grp * 4 + r];

#pragma unroll
        for (int T = 0; T < 4; ++T) {
            int p = 16 * T + col; p = p > 48 ? 48 : p;
            int py = (p * 9363) >> 16;                 // p / 7
            int px = p - 7 * py;
            const f16* base = h1b + (2 * py * 18 + 2 * px) * 8;
            f32x4 vmax = {-1e30f, -1e30f, -1e30f, -1e30f};
#pragma unroll
            for (int q = 0; q < 4; ++q) {
                const f16* bp = base + ((q >> 1) * 18 + (q & 1)) * 8;
                f32x4 c = {0.f, 0.f, 0.f, 0.f};
#pragma unroll
                for (int st = 0; st < 3; ++st) {
                    f16x8 bv = *(const f16x8*)(bp + koff[st]);
                    c = __builtin_amdgcn_mfma_f32_16x16x32_f16(af[st], bv, c, 0, 0, 0);
                }
                vmax = __builtin_elementwise_max(vmax, c);
            }
            if (16 * T + col <= 48) {
#pragma unroll
                for (int r = 0; r < 4; ++r)
                    sfeats[(grp * 4 + r) * 49 + p] = (f16)fmaxf(vmax[r] + cb[r], 0.f);
            }
        }
        // zero FC1 K-pad region (indices 784..799)
        if (lane < 8) *(uint32_t*)(sfeats + 784 + lane * 2) = 0u;
    }
    __syncthreads();                                   // B1

    // ---- stage 3: FC1 via MFMA (wave -> 16 units, B cols = 4 samples) ------
    {
        const f16* wrow = w1p16 + (size_t)(wid * 16 + col) * 800;
        const int scol = col < NS ? col : 0;           // clamp B cols
        const f16* fb = (const f16*)(uni + scol * 2048);
        f32x4 c = {0.f, 0.f, 0.f, 0.f};
#pragma unroll 5
        for (int st = 0; st < 25; ++st) {
            int k0 = st * 32 + grp * 8;
            f16x8 a = *(const f16x8*)(wrow + k0);      // global b128
            f16x8 b = *(const f16x8*)(fb + k0);        // LDS b128
            c = __builtin_amdgcn_mfma_f32_16x16x32_f16(a, b, c, 0, 0, 0);
        }
        if (col < NS) {
            const int u0 = wid * 16 + grp * 4;
            float4 h;
            h.x = fmaxf(c[0] + f1b[u0 + 0], 0.f);
            h.y = fmaxf(c[1] + f1b[u0 + 1], 0.f);
            h.z = fmaxf(c[2] + f1b[u0 + 2], 0.f);
            h.w = fmaxf(c[3] + f1b[u0 + 3], 0.f);
            *(float4*)(shl + col * 64 + u0) = h;
        }
    }
    __syncthreads();                                   // B2

    // ---- stage 4: FC2 (64->4), wave s = sample s ---------------------------
    {
        float hv = shl[wid * 64 + lane];
        float lg[4];
#pragma unroll
        for (int o = 0; o < 4; ++o) {
            float pv = hv * f2w[o * 64 + lane];
#pragma unroll
            for (int sft = 32; sft >= 1; sft >>= 1) pv += __shfl_xor(pv, sft);
            lg[o] = pv + f2b[o];
        }
        if (lane == 0) {
            float4 out4 = make_float4(lg[0], lg[1], lg[2], lg[3]);
            *(float4*)(logits + (size_t)(b0 + wid) * 4) = out4;
        }
    }
}

// -----------------------------------------------------------------------------
// Tail: each of 32 blocks redundantly reduces all logits -> BN stats; thread 0
// runs the (batch-constant) 4-qubit sim; block applies affine to its slice.
// -----------------------------------------------------------------------------
__global__ __launch_bounds__(256) void stats_apply(
    const float* __restrict__ logits, const float* __restrict__ var,
    const float* __restrict__ gamma, const float* __restrict__ beta,
    float* __restrict__ out)
{
    const int tid = threadIdx.x;
    const float4* l4 = (const float4*)logits;

    float t[8] = {0, 0, 0, 0, 0, 0, 0, 0};
#pragma unroll 4
    for (int i = 0; i < 32; ++i) {
        float4 v = l4[tid + 256 * i];
        t[0] += v.x; t[1] += v.y; t[2] += v.z; t[3] += v.w;
        t[4] += v.x * v.x; t[5] += v.y * v.y; t[6] += v.z * v.z; t[7] += v.w * v.w;
    }
#pragma unroll
    for (int sft = 32; sft >= 1; sft >>= 1)
#pragma unroll
        for (int j = 0; j < 8; ++j) t[j] += __shfl_xor(t[j], sft);

    __shared__ float part[4][8];
    __shared__ float prm[8];
    if ((tid & 63) == 0) {
#pragma unroll
        for (int j = 0; j < 8; ++j) part[tid >> 6][j] = t[j];
    }
    __syncthreads();

    if (tid == 0) {
        float sums[8];
#pragma unroll
        for (int j = 0; j < 8; ++j)
            sums[j] = part[0][j] + part[1][j] + part[2][j] + part[3][j];

        // 4-qubit statevector sim (ansatz + CNOT chain; feature-map RZ on
        // |0000> is a global phase -> batch-constant expectations)
        float pr[16], pi[16];
#pragma unroll
        for (int i = 0; i < 16; ++i) { pr[i] = 0.f; pi[i] = 0.f; }
        pr[0] = 1.f;
        for (int q = 0; q < 4; ++q) {
            float a  = var[3 * q], b_ = var[3 * q + 1], c = var[3 * q + 2];
            float ca = cosf(0.5f * a),  sa = sinf(0.5f * a);
            float cb = cosf(0.5f * b_), sb = sinf(0.5f * b_);
            float cc = cosf(0.5f * c),  sc = sinf(0.5f * c);
            float m00r = cb * ca, m00i =  sb * sa;
            float m01r = -sb * ca, m01i = -cb * sa;
            float m10r =  sb * ca, m10i = -cb * sa;
            float m11r =  cb * ca, m11i = -sb * sa;
            float u00r = cc * m00r + sc * m00i, u00i = cc * m00i - sc * m00r;
            float u01r = cc * m01r + sc * m01i, u01i = cc * m01i - sc * m01r;
            float u10r = cc * m10r - sc * m10i, u10i = cc * m10i + sc * m10r;
            float u11r = cc * m11r - sc * m11i, u11i = cc * m11i + sc * m11r;
            int stq = 1 << (3 - q);
            for (int i = 0; i < 16; ++i) {
                if (i & stq) continue;
                int j = i | stq;
                float xr = pr[i], xi = pi[i], yr = pr[j], yi = pi[j];
                pr[i] = u00r * xr - u00i * xi + u01r * yr - u01i * yi;
                pi[i] = u00r * xi + u00i * xr + u01r * yi + u01i * yr;
                pr[j] = u10r * xr - u10i * xi + u11r * yr - u11i * yi;
                pi[j] = u10r * xi + u10i * xr + u11r * yi + u11i * yr;
            }
        }
        for (int c = 0; c < 3; ++c) {
            int scm = 1 << (3 - c), stm = 1 << (2 - c);
            for (int i = 0; i < 16; ++i) {
                if ((i & scm) && !(i & stm)) {
                    int j = i | stm;
                    float tr = pr[i], ti = pi[i];
                    pr[i] = pr[j]; pi[i] = pi[j];
                    pr[j] = tr;    pi[j] = ti;
                }
            }
        }
        float p[16];
#pragma unroll
        for (int i = 0; i < 16; ++i) p[i] = pr[i] * pr[i] + pi[i] * pi[i];
        float e[4];
        for (int k = 0; k < 4; ++k) {
            float s = 0.f;
            for (int i = 0; i < 16; ++i)
                s += ((i >> (3 - k)) & 1) ? -p[i] : p[i];
            e[k] = s;
        }
        const float invB = 1.0f / (float)BATCH;
        for (int j = 0; j < 4; ++j) {
            float mu   = sums[j] * invB;
            float vr   = sums[4 + j] * invB - mu * mu;
            float istd = 1.0f / sqrtf(vr + 1e-5f);
            float scale = gamma[j] * istd;
            prm[j]     = scale;
            prm[4 + j] = beta[j] - mu * scale + e[3 - j];
        }
    }
    __syncthreads();

    const int smp = blockIdx.x * 256 + tid;
    float4 v = l4[smp];
    float4 r;
    r.x = v.x * prm[0] + prm[4];
    r.y = v.y * prm[1] + prm[5];
    r.z = v.z * prm[2] + prm[6];
    r.w = v.w * prm[3] + prm[7];
    ((float4*)out)[smp] = r;
}

extern "C" void kernel_launch(void* const* d_in, const int* in_sizes, int n_in,
                              void* d_out, int out_size, void* d_ws, size_t ws_size,
                              hipStream_t stream) {
    (void)in_sizes; (void)n_in; (void)out_size; (void)ws_size;
    const float* x   = (const float*)d_in[0];
    const float* c1w = (const float*)d_in[1];
    const float* c1b = (const float*)d_in[2];
    const float* c2w = (const float*)d_in[3];
    const float* c2b = (const float*)d_in[4];
    const float* f1w = (const float*)d_in[5];
    const float* f1b = (const float*)d_in[6];
    const float* f2w = (const float*)d_in[7];
    const float* f2b = (const float*)d_in[8];
    const float* gma = (const float*)d_in[9];
    const float* bta = (const float*)d_in[10];
    const float* var = (const float*)d_in[11];
    float* out = (float*)d_out;

    float*    logits = (float*)d_ws;                 // 131072 B
    uint32_t* w1p16  = (uint32_t*)(logits + 32768);  // 102400 B ([64][800] f16)

    pack_weights<<<100, 256, 0, stream>>>(f1w, w1p16);
    fused_cnn<<<BATCH / NS, 256, 0, stream>>>(x, c1w, c1b, c2w, c2b,
                                              (const f16*)w1p16, f1b, f2w, f2b,
                                              logits);
    stats_apply<<<32, 256, 0, stream>>>(logits, var, gma, bta, out);
}

// Round 8
// 135.847 us; speedup vs baseline: 1.5337x; 1.0232x over previous
//
#include <hip/hip_runtime.h>
#include <math.h>
#include <stdint.h>

#define BATCH 8192
#define NS 4            // samples per block = waves per block
#define SLOT 2112       // uni slot stride in bytes (16-bank skew between samples)

typedef _Float16 f16;
typedef _Float16 f16x2 __attribute__((ext_vector_type(2)));
typedef _Float16 f16x8 __attribute__((ext_vector_type(8)));
typedef float f32x4 __attribute__((ext_vector_type(4)));
typedef uint32_t u32x4 __attribute__((ext_vector_type(4)));

__device__ __forceinline__ uint32_t pk2(float a, float b) {
    return __builtin_bit_cast(uint32_t, __builtin_amdgcn_cvt_pkrtz(a, b));
}
__device__ __forceinline__ uint32_t rfl_u(uint32_t v) {
    return (uint32_t)__builtin_amdgcn_readfirstlane((int)v);
}
__device__ __forceinline__ void wave_lds_fence() {
    asm volatile("s_waitcnt lgkmcnt(0)" ::: "memory");
}

// -----------------------------------------------------------------------------
// Pack: f1w fp32 [64][784] -> f16 [64][800], PIXEL-MAJOR k = p*16 + oc
// (matches stage2's vectorized store layout); k >= 784 -> 0.
// -----------------------------------------------------------------------------
__global__ __launch_bounds__(256) void pack_weights(
    const float* __restrict__ f1w, uint32_t* __restrict__ w1p16)
{
    int idx = blockIdx.x * 256 + threadIdx.x;
    if (idx < 25600) {
        int o = idx / 400, pos = idx - o * 400;
        int k0 = 2 * pos, k1 = k0 + 1;
        float v0 = (k0 < 784) ? f1w[o * 784 + (k0 & 15) * 49 + (k0 >> 4)] : 0.f;
        float v1 = (k1 < 784) ? f1w[o * 784 + (k1 & 15) * 49 + (k1 >> 4)] : 0.f;
        w1p16[idx] = pk2(v0, v1);
    }
}

// -----------------------------------------------------------------------------
// Fused CNN. Block = 4 samples, 4 waves (256 thr). Wave s owns sample s through
// stages 0-2 (wave-private LDS, in-order DS pipe, no barriers). Then:
//   B1 -> FC1 MFMA (wave = 16 output units, K=800, B cols = 4 samples)
//   B2 -> FC2 shuffle-reduce -> logits
// LDS 26880 B -> 6 blocks/CU. Sample slots skewed 16 banks apart so FC1's
// cross-sample b128 reads are 2-way (free) instead of 4-way conflicts.
// -----------------------------------------------------------------------------
__global__ __launch_bounds__(256, 6) void fused_cnn(
    const float* __restrict__ x,        // [B,1,28,28]
    const float* __restrict__ c1w,      // [8,9]
    const float* __restrict__ c1b,      // [8]
    const float* __restrict__ c2w,      // [16,8,9]
    const float* __restrict__ c2b,      // [16]
    const f16* __restrict__ w1p16,      // [64][800] f16 packed, pixel-major
    const float* __restrict__ f1b,      // [64]
    const float* __restrict__ f2w,      // [4,64]
    const float* __restrict__ f2b,      // [4]
    float* __restrict__ logits)         // [B,4]
{
    const int tid  = threadIdx.x;
    const int lane = tid & 63;
    const int wid  = tid >> 6;          // wave = sample 0..3
    const int b0   = blockIdx.x * NS;

    __shared__ __align__(16) f16 h1[NS * 16 * 18 * 8];        // 18432 B
    __shared__ __align__(16) unsigned char uni[NS * SLOT];    // 8448 B
    // overlays per sample slot (SLOT bytes, 16-bank skew):
    //   stage0/1: simg : [32 rows][32 cols] f16; image row r at LDS row r+1,
    //             image col c at LDS col c+2 (wrap-pad zeros)
    //   stage2+ : sfeat: [800] f16, PIXEL-MAJOR k = p*16 + oc
    //   FC1+    : shl = (float*)h1 ([4][64] fp32), h1 dead after B1
    float* shl = (float*)h1;

    // ---- per-wave zero of own simg + h1 regions ----------------------------
    {
        uint4 z = make_uint4(0, 0, 0, 0);
        uint4* zs = (uint4*)(uni + wid * SLOT);
        for (int i = lane; i < 128; i += 64) zs[i] = z;
        uint4* zh = (uint4*)(h1 + wid * 2304);
        for (int i = lane; i < 288; i += 64) zh[i] = z;
    }

    // conv1 packed weights -> SGPR (wave-uniform)
    f16x2 wpk[36], bpk[4];
#pragma unroll
    for (int t = 0; t < 9; ++t)
#pragma unroll
        for (int pr = 0; pr < 4; ++pr)
            wpk[t * 4 + pr] = __builtin_bit_cast(f16x2,
                rfl_u(pk2(c1w[(2 * pr) * 9 + t], c1w[(2 * pr + 1) * 9 + t])));
#pragma unroll
    for (int pr = 0; pr < 4; ++pr)
        bpk[pr] = __builtin_bit_cast(f16x2, rfl_u(pk2(c1b[2 * pr], c1b[2 * pr + 1])));

    const int col = lane & 15, grp = lane >> 4;

    // conv2 A-fragment gathered straight from global (L2-hot, once per wave)
    f16x8 af[3];
    int koff[3];
#pragma unroll
    for (int st = 0; st < 3; ++st) {
        int tap = st * 4 + grp;
        if (tap < 9) {
            int ky = tap / 3, kx = tap - 3 * (tap / 3);
            koff[st] = (ky * 18 + kx) * 8;
            float tmp[8];
#pragma unroll
            for (int j = 0; j < 8; ++j) tmp[j] = c2w[(col * 8 + j) * 9 + tap];
            u32x4 t = { pk2(tmp[0], tmp[1]), pk2(tmp[2], tmp[3]),
                        pk2(tmp[4], tmp[5]), pk2(tmp[6], tmp[7]) };
            af[st] = __builtin_bit_cast(f16x8, t);
        } else {
            koff[st] = 0;
            u32x4 t = {0u, 0u, 0u, 0u};
            af[st] = __builtin_bit_cast(f16x8, t);
        }
    }
    wave_lds_fence();

    // ---- stage 0: own image -> padded f16 LDS (aligned b32 writes) ---------
    {
        f16* simg = (f16*)(uni + wid * SLOT);
        const float* xb = x + (size_t)(b0 + wid) * 784;
#pragma unroll 1
        for (int pass = 0; pass < 4; ++pass) {
            int item = pass * 64 + lane;      // float4 index over 196
            if (item < 196) {
                int r = item / 7, c4 = item - 7 * r;
                float4 v = *(const float4*)(xb + r * 28 + c4 * 4);
                int off = (r + 1) * 32 + 2 + 4 * c4;   // 4B-aligned (f16 idx even)
                *(uint32_t*)(simg + off)     = pk2(v.x, v.y);
                *(uint32_t*)(simg + off + 2) = pk2(v.z, v.w);
            }
        }
    }
    wave_lds_fence();

    // ---- stage 1: conv1 + pool + relu (pk_fma, f16 accum) ------------------
    {
        const f16* simg = (const f16*)(uni + wid * SLOT);
        f16* h1s = h1 + wid * 2304;
#pragma unroll 1
        for (int pass = 0; pass < 4; ++pass) {
            int pix = pass * 64 + lane;       // pooled pixel over 196
            if (pix < 196) {
                int py = pix / 14, px = pix - 14 * py;
                f16x2 acc[2][2][4];
#pragma unroll
                for (int qy = 0; qy < 2; ++qy)
#pragma unroll
                for (int qx = 0; qx < 2; ++qx)
#pragma unroll
                for (int pr = 0; pr < 4; ++pr) acc[qy][qx][pr] = bpk[pr];

#pragma unroll
                for (int rr = 0; rr < 4; ++rr) {
                    const f16* rb = simg + (2 * py + rr) * 32 + 2 * px;
                    f16x2 A = *(const f16x2*)(rb);
                    f16x2 Bv = *(const f16x2*)(rb + 2);
                    f16x2 C = *(const f16x2*)(rb + 4);
                    f16 P[4] = { A[1], Bv[0], Bv[1], C[0] };
                    f16x2 sp[4];
#pragma unroll
                    for (int i = 0; i < 4; ++i) { sp[i][0] = P[i]; sp[i][1] = P[i]; }
#pragma unroll
                    for (int qy = 0; qy < 2; ++qy) {
                        int ky = rr - qy;
                        if (ky < 0 || ky > 2) continue;
#pragma unroll
                        for (int qx = 0; qx < 2; ++qx)
#pragma unroll
                        for (int kx = 0; kx < 3; ++kx) {
#pragma unroll
                            for (int pr = 0; pr < 4; ++pr)
                                acc[qy][qx][pr] = __builtin_elementwise_fma(
                                    sp[qx + kx], wpk[(ky * 3 + kx) * 4 + pr],
                                    acc[qy][qx][pr]);
                        }
                    }
                }
                f16x2 z; z[0] = (f16)0.f; z[1] = (f16)0.f;
                uint32_t ov[4];
#pragma unroll
                for (int pr = 0; pr < 4; ++pr) {
                    f16x2 m = __builtin_elementwise_max(
                        __builtin_elementwise_max(acc[0][0][pr], acc[0][1][pr]),
                        __builtin_elementwise_max(acc[1][0][pr], acc[1][1][pr]));
                    m = __builtin_elementwise_max(m, z);
                    ov[pr] = __builtin_bit_cast(uint32_t, m);
                }
                uint4 val = make_uint4(ov[0], ov[1], ov[2], ov[3]);
                *(uint4*)(h1s + ((py + 1) * 18 + (px + 1)) * 8) = val;
            }
        }
    }
    wave_lds_fence();

    // ---- stage 2: conv2 MFMA, N = 16 pooled pixels, pool-in-registers ------
    {
        const f16* h1b = h1 + wid * 2304;
        f16* sfeats = (f16*)(uni + wid * SLOT);
        f32x4 cb;
#pragma unroll
        for (int r = 0; r < 4; ++r) cb[r] = c2b[grp * 4 + r];

#pragma unroll
        for (int T = 0; T < 4; ++T) {
            int p = 16 * T + col; p = p > 48 ? 48 : p;
            int py = (p * 9363) >> 16;                 // p / 7
            int px = p - 7 * py;
            const f16* base = h1b + (2 * py * 18 + 2 * px) * 8;
            f32x4 vmax = {-1e30f, -1e30f, -1e30f, -1e30f};
#pragma unroll
            for (int q = 0; q < 4; ++q) {
                const f16* bp = base + ((q >> 1) * 18 + (q & 1)) * 8;
                f32x4 c = {0.f, 0.f, 0.f, 0.f};
#pragma unroll
                for (int st = 0; st < 3; ++st) {
                    f16x8 bv = *(const f16x8*)(bp + koff[st]);
                    c = __builtin_amdgcn_mfma_f32_16x16x32_f16(af[st], bv, c, 0, 0, 0);
                }
                vmax = __builtin_elementwise_max(vmax, c);
            }
            if (16 * T + col <= 48) {
                // pixel-major, vectorized: sfeat[p*16 + grp*4 .. +3]
                uint2 val;
                val.x = pk2(fmaxf(vmax[0] + cb[0], 0.f), fmaxf(vmax[1] + cb[1], 0.f));
                val.y = pk2(fmaxf(vmax[2] + cb[2], 0.f), fmaxf(vmax[3] + cb[3], 0.f));
                *(uint2*)(sfeats + p * 16 + grp * 4) = val;
            }
        }
        // zero FC1 K-pad region (indices 784..799)
        if (lane < 4) *(uint2*)(sfeats + 784 + lane * 4) = make_uint2(0u, 0u);
    }
    __syncthreads();                                   // B1

    // ---- stage 3: FC1 via MFMA (wave -> 16 units, B cols = 4 samples) ------
    {
        const f16* wrow = w1p16 + (size_t)(wid * 16 + col) * 800;
        const int scol = col < NS ? col : 0;           // clamp B cols
        const f16* fb = (const f16*)(uni + scol * SLOT);
        f32x4 c = {0.f, 0.f, 0.f, 0.f};
#pragma unroll 5
        for (int st = 0; st < 25; ++st) {
            int k0 = st * 32 + grp * 8;
            f16x8 a = *(const f16x8*)(wrow + k0);      // global b128
            f16x8 b = *(const f16x8*)(fb + k0);        // LDS b128 (2-way max)
            c = __builtin_amdgcn_mfma_f32_16x16x32_f16(a, b, c, 0, 0, 0);
        }
        if (col < NS) {
            const int u0 = wid * 16 + grp * 4;
            float4 h;
            h.x = fmaxf(c[0] + f1b[u0 + 0], 0.f);
            h.y = fmaxf(c[1] + f1b[u0 + 1], 0.f);
            h.z = fmaxf(c[2] + f1b[u0 + 2], 0.f);
            h.w = fmaxf(c[3] + f1b[u0 + 3], 0.f);
            *(float4*)(shl + col * 64 + u0) = h;
        }
    }
    __syncthreads();                                   // B2

    // ---- stage 4: FC2 (64->4), wave s = sample s ---------------------------
    {
        float hv = shl[wid * 64 + lane];
        float lg[4];
#pragma unroll
        for (int o = 0; o < 4; ++o) {
            float pv = hv * f2w[o * 64 + lane];
#pragma unroll
            for (int sft = 32; sft >= 1; sft >>= 1) pv += __shfl_xor(pv, sft);
            lg[o] = pv + f2b[o];
        }
        if (lane == 0) {
            float4 out4 = make_float4(lg[0], lg[1], lg[2], lg[3]);
            *(float4*)(logits + (size_t)(b0 + wid) * 4) = out4;
        }
    }
}

// -----------------------------------------------------------------------------
// Tail: each of 32 blocks redundantly reduces all logits -> BN stats; thread 0
// runs the (batch-constant) 4-qubit sim; block applies affine to its slice.
// -----------------------------------------------------------------------------
__global__ __launch_bounds__(256) void stats_apply(
    const float* __restrict__ logits, const float* __restrict__ var,
    const float* __restrict__ gamma, const float* __restrict__ beta,
    float* __restrict__ out)
{
    const int tid = threadIdx.x;
    const float4* l4 = (const float4*)logits;

    float t[8] = {0, 0, 0, 0, 0, 0, 0, 0};
#pragma unroll 4
    for (int i = 0; i < 32; ++i) {
        float4 v = l4[tid + 256 * i];
        t[0] += v.x; t[1] += v.y; t[2] += v.z; t[3] += v.w;
        t[4] += v.x * v.x; t[5] += v.y * v.y; t[6] += v.z * v.z; t[7] += v.w * v.w;
    }
#pragma unroll
    for (int sft = 32; sft >= 1; sft >>= 1)
#pragma unroll
        for (int j = 0; j < 8; ++j) t[j] += __shfl_xor(t[j], sft);

    __shared__ float part[4][8];
    __shared__ float prm[8];
    if ((tid & 63) == 0) {
#pragma unroll
        for (int j = 0; j < 8; ++j) part[tid >> 6][j] = t[j];
    }
    __syncthreads();

    if (tid == 0) {
        float sums[8];
#pragma unroll
        for (int j = 0; j < 8; ++j)
            sums[j] = part[0][j] + part[1][j] + part[2][j] + part[3][j];

        // 4-qubit statevector sim (ansatz + CNOT chain; feature-map RZ on
        // |0000> is a global phase -> batch-constant expectations)
        float pr[16], pi[16];
#pragma unroll
        for (int i = 0; i < 16; ++i) { pr[i] = 0.f; pi[i] = 0.f; }
        pr[0] = 1.f;
        for (int q = 0; q < 4; ++q) {
            float a  = var[3 * q], b_ = var[3 * q + 1], c = var[3 * q + 2];
            float ca = cosf(0.5f * a),  sa = sinf(0.5f * a);
            float cb = cosf(0.5f * b_), sb = sinf(0.5f * b_);
            float cc = cosf(0.5f * c),  sc = sinf(0.5f * c);
            float m00r = cb * ca, m00i =  sb * sa;
            float m01r = -sb * ca, m01i = -cb * sa;
            float m10r =  sb * ca, m10i = -cb * sa;
            float m11r =  cb * ca, m11i = -sb * sa;
            float u00r = cc * m00r + sc * m00i, u00i = cc * m00i - sc * m00r;
            float u01r = cc * m01r + sc * m01i, u01i = cc * m01i - sc * m01r;
            float u10r = cc * m10r - sc * m10i, u10i = cc * m10i + sc * m10r;
            float u11r = cc * m11r - sc * m11i, u11i = cc * m11i + sc * m11r;
            int stq = 1 << (3 - q);
            for (int i = 0; i < 16; ++i) {
                if (i & stq) continue;
                int j = i | stq;
                float xr = pr[i], xi = pi[i], yr = pr[j], yi = pi[j];
                pr[i] = u00r * xr - u00i * xi + u01r * yr - u01i * yi;
                pi[i] = u00r * xi + u00i * xr + u01r * yi + u01i * yr;
                pr[j] = u10r * xr - u10i * xi + u11r * yr - u11i * yi;
                pi[j] = u10r * xi + u10i * xr + u11r * yi + u11i * yr;
            }
        }
        for (int c = 0; c < 3; ++c) {
            int scm = 1 << (3 - c), stm = 1 << (2 - c);
            for (int i = 0; i < 16; ++i) {
                if ((i & scm) && !(i & stm)) {
                    int j = i | stm;
                    float tr = pr[i], ti = pi[i];
                    pr[i] = pr[j]; pi[i] = pi[j];
                    pr[j] = tr;    pi[j] = ti;
                }
            }
        }
        float p[16];
#pragma unroll
        for (int i = 0; i < 16; ++i) p[i] = pr[i] * pr[i] + pi[i] * pi[i];
        float e[4];
        for (int k = 0; k < 4; ++k) {
            float s = 0.f;
            for (int i = 0; i < 16; ++i)
                s += ((i >> (3 - k)) & 1) ? -p[i] : p[i];
            e[k] = s;
        }
        const float invB = 1.0f / (float)BATCH;
        for (int j = 0; j < 4; ++j) {
            float mu   = sums[j] * invB;
            float vr   = sums[4 + j] * invB - mu * mu;
            float istd = 1.0f / sqrtf(vr + 1e-5f);
            float scale = gamma[j] * istd;
            prm[j]     = scale;
            prm[4 + j] = beta[j] - mu * scale + e[3 - j];
        }
    }
    __syncthreads();

    const int smp = blockIdx.x * 256 + tid;
    float4 v = l4[smp];
    float4 r;
    r.x = v.x * prm[0] + prm[4];
    r.y = v.y * prm[1] + prm[5];
    r.z = v.z * prm[2] + prm[6];
    r.w = v.w * prm[3] + prm[7];
    ((float4*)out)[smp] = r;
}

extern "C" void kernel_launch(void* const* d_in, const int* in_sizes, int n_in,
                              void* d_out, int out_size, void* d_ws, size_t ws_size,
                              hipStream_t stream) {
    (void)in_sizes; (void)n_in; (void)out_size; (void)ws_size;
    const float* x   = (const float*)d_in[0];
    const float* c1w = (const float*)d_in[1];
    const float* c1b = (const float*)d_in[2];
    const float* c2w = (const float*)d_in[3];
    const float* c2b = (const float*)d_in[4];
    const float* f1w = (const float*)d_in[5];
    const float* f1b = (const float*)d_in[6];
    const float* f2w = (const float*)d_in[7];
    const float* f2b = (const float*)d_in[8];
    const float* gma = (const float*)d_in[9];
    const float* bta = (const float*)d_in[10];
    const float* var = (const float*)d_in[11];
    float* out = (float*)d_out;

    float*    logits = (float*)d_ws;                 // 131072 B
    uint32_t* w1p16  = (uint32_t*)(logits + 32768);  // 102400 B ([64][800] f16)

    pack_weights<<<100, 256, 0, stream>>>(f1w, w1p16);
    fused_cnn<<<BATCH / NS, 256, 0, stream>>>(x, c1w, c1b, c2w, c2b,
                                              (const f16*)w1p16, f1b, f2w, f2b,
                                              logits);
    stats_apply<<<32, 256, 0, stream>>>(logits, var, gma, bta, out);
}

// Round 9
// 125.456 us; speedup vs baseline: 1.6608x; 1.0828x over previous
//
#include <hip/hip_runtime.h>
#include <math.h>
#include <stdint.h>

#define BATCH 8192
#define NS 4            // samples per block = waves per block
#define SLOT 2112       // uni slot stride in bytes (16-bank skew between samples)

typedef _Float16 f16;
typedef _Float16 f16x2 __attribute__((ext_vector_type(2)));
typedef _Float16 f16x8 __attribute__((ext_vector_type(8)));
typedef float f32x4 __attribute__((ext_vector_type(4)));
typedef uint32_t u32x4 __attribute__((ext_vector_type(4)));

__device__ __forceinline__ uint32_t pk2(float a, float b) {
    return __builtin_bit_cast(uint32_t, __builtin_amdgcn_cvt_pkrtz(a, b));
}
__device__ __forceinline__ uint32_t rfl_u(uint32_t v) {
    return (uint32_t)__builtin_amdgcn_readfirstlane((int)v);
}
__device__ __forceinline__ void wave_lds_fence() {
    asm volatile("s_waitcnt lgkmcnt(0)" ::: "memory");
}

// -----------------------------------------------------------------------------
// Pack:
//  w1p16 [64][800] f16, PIXEL-MAJOR k = p*16 + oc (k>=784 -> 0)
//  w2a   [16][96]  f16, k = tap*8 + ic (k>=72 -> 0): A-operand for conv2 MFMA,
//        row = oc, so a lane's fragment is one aligned b128.
// -----------------------------------------------------------------------------
__global__ __launch_bounds__(256) void pack_weights(
    const float* __restrict__ f1w, const float* __restrict__ c2w,
    uint32_t* __restrict__ w1p16, uint32_t* __restrict__ w2a)
{
    int idx = blockIdx.x * 256 + threadIdx.x;
    if (idx < 25600) {
        int o = idx / 400, pos = idx - o * 400;
        int k0 = 2 * pos, k1 = k0 + 1;
        float v0 = (k0 < 784) ? f1w[o * 784 + (k0 & 15) * 49 + (k0 >> 4)] : 0.f;
        float v1 = (k1 < 784) ? f1w[o * 784 + (k1 & 15) * 49 + (k1 >> 4)] : 0.f;
        w1p16[idx] = pk2(v0, v1);
    } else if (idx < 25600 + 768) {
        int i = idx - 25600;
        int oc = i / 48, pos = i - oc * 48;
        int k0 = 2 * pos, k1 = k0 + 1;
        float v0 = (k0 < 72) ? c2w[oc * 72 + (k0 & 7) * 9 + (k0 >> 3)] : 0.f;
        float v1 = (k1 < 72) ? c2w[oc * 72 + (k1 & 7) * 9 + (k1 >> 3)] : 0.f;
        w2a[i] = pk2(v0, v1);
    }
}

// -----------------------------------------------------------------------------
// Fused CNN. Block = 4 samples, 4 waves (256 thr). Wave s owns sample s through
// stages 0-2 (wave-private LDS, in-order DS pipe, no barriers). Then:
//   B1 -> FC1 MFMA (wave = 16 output units, K=800, B cols = 4 samples)
//   B2 -> FC2 shuffle-reduce -> logits
// LDS 26880 B -> 6 blocks/CU. Latency fixes this round: batched stage-0 global
// loads (one vmcnt wait), b128 conv2-weight loads, FC1 5-deep weight prefetch
// issued before barrier B1.
// -----------------------------------------------------------------------------
__global__ __launch_bounds__(256, 6) void fused_cnn(
    const float* __restrict__ x,        // [B,1,28,28]
    const float* __restrict__ c1w,      // [8,9]
    const float* __restrict__ c1b,      // [8]
    const f16* __restrict__ w2a,        // [16][96] packed conv2 A
    const float* __restrict__ c2b,      // [16]
    const f16* __restrict__ w1p16,      // [64][800] f16 packed, pixel-major
    const float* __restrict__ f1b,      // [64]
    const float* __restrict__ f2w,      // [4,64]
    const float* __restrict__ f2b,      // [4]
    float* __restrict__ logits)         // [B,4]
{
    const int tid  = threadIdx.x;
    const int lane = tid & 63;
    const int wid  = tid >> 6;          // wave = sample 0..3
    const int b0   = blockIdx.x * NS;

    __shared__ __align__(16) f16 h1[NS * 16 * 18 * 8];        // 18432 B
    __shared__ __align__(16) unsigned char uni[NS * SLOT];    // 8448 B
    // overlays per sample slot (SLOT bytes, 16-bank skew):
    //   stage0/1: simg : [32 rows][32 cols] f16; image row r at LDS row r+1,
    //             image col c at LDS col c+2 (wrap-pad zeros)
    //   stage2+ : sfeat: [800] f16, PIXEL-MAJOR k = p*16 + oc
    //   FC1+    : shl = (float*)h1 ([4][64] fp32), h1 dead after B1
    float* shl = (float*)h1;

    const int col = lane & 15, grp = lane >> 4;

    // ---- early VMEM issues: image (stage0), conv2 A, conv1 weights ---------
    const float* xb = x + (size_t)(b0 + wid) * 784;
    const int i0 = lane, i1 = lane + 64, i2 = lane + 128;
    const int r0i = i0 / 7, c0i = i0 - 7 * r0i;
    const int r1i = i1 / 7, c1i = i1 - 7 * r1i;
    const int r2i = i2 / 7, c2i = i2 - 7 * r2i;
    float4 v0 = *(const float4*)(xb + r0i * 28 + c0i * 4);
    float4 v1 = *(const float4*)(xb + r1i * 28 + c1i * 4);
    float4 v2 = *(const float4*)(xb + r2i * 28 + c2i * 4);
    float4 v3 = make_float4(0.f, 0.f, 0.f, 0.f);
    if (lane < 4) v3 = *(const float4*)(xb + (lane + 192) / 7 * 28 + ((lane + 192) % 7) * 4);

    // conv2 A fragment: 3 aligned b128 loads (zeros for pad taps baked in)
    f16x8 af[3];
    int koff[3];
#pragma unroll
    for (int st = 0; st < 3; ++st) {
        af[st] = *(const f16x8*)(w2a + col * 96 + st * 32 + grp * 8);
        int tap = st * 4 + grp;
        if (tap < 9) {
            int ky = tap / 3, kx = tap - 3 * (tap / 3);
            koff[st] = (ky * 18 + kx) * 8;
        } else koff[st] = 0;
    }

    // ---- per-wave zero of own simg + h1 regions ----------------------------
    {
        uint4 z = make_uint4(0, 0, 0, 0);
        uint4* zs = (uint4*)(uni + wid * SLOT);
        for (int i = lane; i < 128; i += 64) zs[i] = z;
        uint4* zh = (uint4*)(h1 + wid * 2304);
        for (int i = lane; i < 288; i += 64) zh[i] = z;
    }

    // conv1 packed weights -> SGPR (wave-uniform)
    f16x2 wpk[36], bpk[4];
#pragma unroll
    for (int t = 0; t < 9; ++t)
#pragma unroll
        for (int pr = 0; pr < 4; ++pr)
            wpk[t * 4 + pr] = __builtin_bit_cast(f16x2,
                rfl_u(pk2(c1w[(2 * pr) * 9 + t], c1w[(2 * pr + 1) * 9 + t])));
#pragma unroll
    for (int pr = 0; pr < 4; ++pr)
        bpk[pr] = __builtin_bit_cast(f16x2, rfl_u(pk2(c1b[2 * pr], c1b[2 * pr + 1])));
    wave_lds_fence();

    // ---- stage 0: image -> padded f16 LDS (batched loads done above) -------
    {
        f16* simg = (f16*)(uni + wid * SLOT);
        int o0 = (r0i + 1) * 32 + 2 + 4 * c0i;
        *(uint32_t*)(simg + o0)     = pk2(v0.x, v0.y);
        *(uint32_t*)(simg + o0 + 2) = pk2(v0.z, v0.w);
        int o1 = (r1i + 1) * 32 + 2 + 4 * c1i;
        *(uint32_t*)(simg + o1)     = pk2(v1.x, v1.y);
        *(uint32_t*)(simg + o1 + 2) = pk2(v1.z, v1.w);
        int o2 = (r2i + 1) * 32 + 2 + 4 * c2i;
        *(uint32_t*)(simg + o2)     = pk2(v2.x, v2.y);
        *(uint32_t*)(simg + o2 + 2) = pk2(v2.z, v2.w);
        if (lane < 4) {
            int it = lane + 192;
            int o3 = (it / 7 + 1) * 32 + 2 + 4 * (it % 7);
            *(uint32_t*)(simg + o3)     = pk2(v3.x, v3.y);
            *(uint32_t*)(simg + o3 + 2) = pk2(v3.z, v3.w);
        }
    }
    wave_lds_fence();

    // ---- stage 1: conv1 + pool + relu (pk_fma, f16 accum) ------------------
    {
        const f16* simg = (const f16*)(uni + wid * SLOT);
        f16* h1s = h1 + wid * 2304;
#pragma unroll 1
        for (int pass = 0; pass < 4; ++pass) {
            int pix = pass * 64 + lane;       // pooled pixel over 196
            if (pix < 196) {
                int py = pix / 14, px = pix - 14 * py;
                f16x2 acc[2][2][4];
#pragma unroll
                for (int qy = 0; qy < 2; ++qy)
#pragma unroll
                for (int qx = 0; qx < 2; ++qx)
#pragma unroll
                for (int pr = 0; pr < 4; ++pr) acc[qy][qx][pr] = bpk[pr];

#pragma unroll
                for (int rr = 0; rr < 4; ++rr) {
                    const f16* rb = simg + (2 * py + rr) * 32 + 2 * px;
                    f16x2 A = *(const f16x2*)(rb);
                    f16x2 Bv = *(const f16x2*)(rb + 2);
                    f16x2 C = *(const f16x2*)(rb + 4);
                    f16 P[4] = { A[1], Bv[0], Bv[1], C[0] };
                    f16x2 sp[4];
#pragma unroll
                    for (int i = 0; i < 4; ++i) { sp[i][0] = P[i]; sp[i][1] = P[i]; }
#pragma unroll
                    for (int qy = 0; qy < 2; ++qy) {
                        int ky = rr - qy;
                        if (ky < 0 || ky > 2) continue;
#pragma unroll
                        for (int qx = 0; qx < 2; ++qx)
#pragma unroll
                        for (int kx = 0; kx < 3; ++kx) {
#pragma unroll
                            for (int pr = 0; pr < 4; ++pr)
                                acc[qy][qx][pr] = __builtin_elementwise_fma(
                                    sp[qx + kx], wpk[(ky * 3 + kx) * 4 + pr],
                                    acc[qy][qx][pr]);
                        }
                    }
                }
                f16x2 z; z[0] = (f16)0.f; z[1] = (f16)0.f;
                uint32_t ov[4];
#pragma unroll
                for (int pr = 0; pr < 4; ++pr) {
                    f16x2 m = __builtin_elementwise_max(
                        __builtin_elementwise_max(acc[0][0][pr], acc[0][1][pr]),
                        __builtin_elementwise_max(acc[1][0][pr], acc[1][1][pr]));
                    m = __builtin_elementwise_max(m, z);
                    ov[pr] = __builtin_bit_cast(uint32_t, m);
                }
                uint4 val = make_uint4(ov[0], ov[1], ov[2], ov[3]);
                *(uint4*)(h1s + ((py + 1) * 18 + (px + 1)) * 8) = val;
            }
        }
    }
    wave_lds_fence();

    // ---- stage 2: conv2 MFMA, N = 16 pooled pixels, pool-in-registers ------
    {
        const f16* h1b = h1 + wid * 2304;
        f16* sfeats = (f16*)(uni + wid * SLOT);
        f32x4 cb;
#pragma unroll
        for (int r = 0; r < 4; ++r) cb[r] = c2b[grp * 4 + r];

#pragma unroll
        for (int T = 0; T < 4; ++T) {
            int p = 16 * T + col; p = p > 48 ? 48 : p;
            int py = (p * 9363) >> 16;                 // p / 7
            int px = p - 7 * py;
            const f16* base = h1b + (2 * py * 18 + 2 * px) * 8;
            f32x4 vmax = {-1e30f, -1e30f, -1e30f, -1e30f};
#pragma unroll
            for (int q = 0; q < 4; ++q) {
                const f16* bp = base + ((q >> 1) * 18 + (q & 1)) * 8;
                f32x4 c = {0.f, 0.f, 0.f, 0.f};
#pragma unroll
                for (int st = 0; st < 3; ++st) {
                    f16x8 bv = *(const f16x8*)(bp + koff[st]);
                    c = __builtin_amdgcn_mfma_f32_16x16x32_f16(af[st], bv, c, 0, 0, 0);
                }
                vmax = __builtin_elementwise_max(vmax, c);
            }
            if (16 * T + col <= 48) {
                uint2 val;
                val.x = pk2(fmaxf(vmax[0] + cb[0], 0.f), fmaxf(vmax[1] + cb[1], 0.f));
                val.y = pk2(fmaxf(vmax[2] + cb[2], 0.f), fmaxf(vmax[3] + cb[3], 0.f));
                *(uint2*)(sfeats + p * 16 + grp * 4) = val;
            }
        }
        // zero FC1 K-pad region (indices 784..799)
        if (lane < 4) *(uint2*)(sfeats + 784 + lane * 4) = make_uint2(0u, 0u);
    }

    // ---- FC1 weight prefetch (VMEM, legal to straddle the barrier) ---------
    const f16* wrow = w1p16 + (size_t)(wid * 16 + col) * 800 + grp * 8;
    f16x8 pa0 = *(const f16x8*)(wrow + 0 * 32);
    f16x8 pa1 = *(const f16x8*)(wrow + 1 * 32);
    f16x8 pa2 = *(const f16x8*)(wrow + 2 * 32);
    f16x8 pa3 = *(const f16x8*)(wrow + 3 * 32);
    f16x8 pa4 = *(const f16x8*)(wrow + 4 * 32);

    __syncthreads();                                   // B1

    // ---- stage 3: FC1 via MFMA (wave -> 16 units, B cols = 4 samples) ------
    {
        const int scol = col < NS ? col : 0;           // clamp B cols
        const f16* fb = (const f16*)(uni + scol * SLOT) + grp * 8;
        f32x4 c = {0.f, 0.f, 0.f, 0.f};
        c = __builtin_amdgcn_mfma_f32_16x16x32_f16(pa0, *(const f16x8*)(fb + 0 * 32), c, 0, 0, 0);
        c = __builtin_amdgcn_mfma_f32_16x16x32_f16(pa1, *(const f16x8*)(fb + 1 * 32), c, 0, 0, 0);
        c = __builtin_amdgcn_mfma_f32_16x16x32_f16(pa2, *(const f16x8*)(fb + 2 * 32), c, 0, 0, 0);
        c = __builtin_amdgcn_mfma_f32_16x16x32_f16(pa3, *(const f16x8*)(fb + 3 * 32), c, 0, 0, 0);
        c = __builtin_amdgcn_mfma_f32_16x16x32_f16(pa4, *(const f16x8*)(fb + 4 * 32), c, 0, 0, 0);
#pragma unroll 5
        for (int st = 5; st < 25; ++st) {
            f16x8 a = *(const f16x8*)(wrow + st * 32);
            f16x8 b = *(const f16x8*)(fb + st * 32);
            c = __builtin_amdgcn_mfma_f32_16x16x32_f16(a, b, c, 0, 0, 0);
        }
        if (col < NS) {
            const int u0 = wid * 16 + grp * 4;
            float4 h;
            h.x = fmaxf(c[0] + f1b[u0 + 0], 0.f);
            h.y = fmaxf(c[1] + f1b[u0 + 1], 0.f);
            h.z = fmaxf(c[2] + f1b[u0 + 2], 0.f);
            h.w = fmaxf(c[3] + f1b[u0 + 3], 0.f);
            *(float4*)(shl + col * 64 + u0) = h;
        }
    }
    __syncthreads();                                   // B2

    // ---- stage 4: FC2 (64->4), wave s = sample s ---------------------------
    {
        float hv = shl[wid * 64 + lane];
        float lg[4];
#pragma unroll
        for (int o = 0; o < 4; ++o) {
            float pv = hv * f2w[o * 64 + lane];
#pragma unroll
            for (int sft = 32; sft >= 1; sft >>= 1) pv += __shfl_xor(pv, sft);
            lg[o] = pv + f2b[o];
        }
        if (lane == 0) {
            float4 out4 = make_float4(lg[0], lg[1], lg[2], lg[3]);
            *(float4*)(logits + (size_t)(b0 + wid) * 4) = out4;
        }
    }
}

// -----------------------------------------------------------------------------
// Tail: each of 32 blocks redundantly reduces all logits -> BN stats; thread 0
// runs the (batch-constant) 4-qubit sim; block applies affine to its slice.
// -----------------------------------------------------------------------------
__global__ __launch_bounds__(256) void stats_apply(
    const float* __restrict__ logits, const float* __restrict__ var,
    const float* __restrict__ gamma, const float* __restrict__ beta,
    float* __restrict__ out)
{
    const int tid = threadIdx.x;
    const float4* l4 = (const float4*)logits;

    float t[8] = {0, 0, 0, 0, 0, 0, 0, 0};
#pragma unroll 4
    for (int i = 0; i < 32; ++i) {
        float4 v = l4[tid + 256 * i];
        t[0] += v.x; t[1] += v.y; t[2] += v.z; t[3] += v.w;
        t[4] += v.x * v.x; t[5] += v.y * v.y; t[6] += v.z * v.z; t[7] += v.w * v.w;
    }
#pragma unroll
    for (int sft = 32; sft >= 1; sft >>= 1)
#pragma unroll
        for (int j = 0; j < 8; ++j) t[j] += __shfl_xor(t[j], sft);

    __shared__ float part[4][8];
    __shared__ float prm[8];
    if ((tid & 63) == 0) {
#pragma unroll
        for (int j = 0; j < 8; ++j) part[tid >> 6][j] = t[j];
    }
    __syncthreads();

    if (tid == 0) {
        float sums[8];
#pragma unroll
        for (int j = 0; j < 8; ++j)
            sums[j] = part[0][j] + part[1][j] + part[2][j] + part[3][j];

        // 4-qubit statevector sim (ansatz + CNOT chain; feature-map RZ on
        // |0000> is a global phase -> batch-constant expectations)
        float pr[16], pi[16];
#pragma unroll
        for (int i = 0; i < 16; ++i) { pr[i] = 0.f; pi[i] = 0.f; }
        pr[0] = 1.f;
        for (int q = 0; q < 4; ++q) {
            float a  = var[3 * q], b_ = var[3 * q + 1], c = var[3 * q + 2];
            float ca = cosf(0.5f * a),  sa = sinf(0.5f * a);
            float cb = cosf(0.5f * b_), sb = sinf(0.5f * b_);
            float cc = cosf(0.5f * c),  sc = sinf(0.5f * c);
            float m00r = cb * ca, m00i =  sb * sa;
            float m01r = -sb * ca, m01i = -cb * sa;
            float m10r =  sb * ca, m10i = -cb * sa;
            float m11r =  cb * ca, m11i = -sb * sa;
            float u00r = cc * m00r + sc * m00i, u00i = cc * m00i - sc * m00r;
            float u01r = cc * m01r + sc * m01i, u01i = cc * m01i - sc * m01r;
            float u10r = cc * m10r - sc * m10i, u10i = cc * m10i + sc * m10r;
            float u11r = cc * m11r - sc * m11i, u11i = cc * m11i + sc * m11r;
            int stq = 1 << (3 - q);
            for (int i = 0; i < 16; ++i) {
                if (i & stq) continue;
                int j = i | stq;
                float xr = pr[i], xi = pi[i], yr = pr[j], yi = pi[j];
                pr[i] = u00r * xr - u00i * xi + u01r * yr - u01i * yi;
                pi[i] = u00r * xi + u00i * xr + u01r * yi + u01i * yr;
                pr[j] = u10r * xr - u10i * xi + u11r * yr - u11i * yi;
                pi[j] = u10r * xi + u10i * xr + u11r * yi + u11i * yr;
            }
        }
        for (int c = 0; c < 3; ++c) {
            int scm = 1 << (3 - c), stm = 1 << (2 - c);
            for (int i = 0; i < 16; ++i) {
                if ((i & scm) && !(i & stm)) {
                    int j = i | stm;
                    float tr = pr[i], ti = pi[i];
                    pr[i] = pr[j]; pi[i] = pi[j];
                    pr[j] = tr;    pi[j] = ti;
                }
            }
        }
        float p[16];
#pragma unroll
        for (int i = 0; i < 16; ++i) p[i] = pr[i] * pr[i] + pi[i] * pi[i];
        float e[4];
        for (int k = 0; k < 4; ++k) {
            float s = 0.f;
            for (int i = 0; i < 16; ++i)
                s += ((i >> (3 - k)) & 1) ? -p[i] : p[i];
            e[k] = s;
        }
        const float invB = 1.0f / (float)BATCH;
        for (int j = 0; j < 4; ++j) {
            float mu   = sums[j] * invB;
            float vr   = sums[4 + j] * invB - mu * mu;
            float istd = 1.0f / sqrtf(vr + 1e-5f);
            float scale = gamma[j] * istd;
            prm[j]     = scale;
            prm[4 + j] = beta[j] - mu * scale + e[3 - j];
        }
    }
    __syncthreads();

    const int smp = blockIdx.x * 256 + tid;
    float4 v = l4[smp];
    float4 r;
    r.x = v.x * prm[0] + prm[4];
    r.y = v.y * prm[1] + prm[5];
    r.z = v.z * prm[2] + prm[6];
    r.w = v.w * prm[3] + prm[7];
    ((float4*)out)[smp] = r;
}

extern "C" void kernel_launch(void* const* d_in, const int* in_sizes, int n_in,
                              void* d_out, int out_size, void* d_ws, size_t ws_size,
                              hipStream_t stream) {
    (void)in_sizes; (void)n_in; (void)out_size; (void)ws_size;
    const float* x   = (const float*)d_in[0];
    const float* c1w = (const float*)d_in[1];
    const float* c1b = (const float*)d_in[2];
    const float* c2w = (const float*)d_in[3];
    const float* c2b = (const float*)d_in[4];
    const float* f1w = (const float*)d_in[5];
    const float* f1b = (const float*)d_in[6];
    const float* f2w = (const float*)d_in[7];
    const float* f2b = (const float*)d_in[8];
    const float* gma = (const float*)d_in[9];
    const float* bta = (const float*)d_in[10];
    const float* var = (const float*)d_in[11];
    float* out = (float*)d_out;

    float*    logits = (float*)d_ws;                 // 131072 B
    uint32_t* w1p16  = (uint32_t*)(logits + 32768);  // 102400 B ([64][800] f16)
    uint32_t* w2a    = w1p16 + 25600;                // 3072 B   ([16][96] f16)

    pack_weights<<<103, 256, 0, stream>>>(f1w, c2w, w1p16, w2a);
    fused_cnn<<<BATCH / NS, 256, 0, stream>>>(x, c1w, c1b, (const f16*)w2a, c2b,
                                              (const f16*)w1p16, f1b, f2w, f2b,
                                              logits);
    stats_apply<<<32, 256, 0, stream>>>(logits, var, gma, bta, out);
}